// Round 1
// baseline (1344.073 us; speedup 1.0000x reference)
//
#include <hip/hip_runtime.h>
#include <math.h>

// LRENet_2: L=4, AD=D=512, T=64, N=4096, NC=2, PROJ=256, HID=2048, CAP=16
#define LNUM 4
#define ADIM 512
#define TTOK 64
#define NSEQ 4096
#define HIDE 2048
#define CAPE 16
#define EPSV 1e-5f

// ---------------- workspace layout (float offsets) ----------------
#define OFF_MU      0
#define OFF_RSTD    (OFF_MU   + LNUM*NSEQ)
#define OFF_KT      (OFF_RSTD + LNUM*NSEQ)
#define OFF_VT      (OFF_KT   + LNUM*512*NSEQ)
#define OFF_KMAX    (OFF_VT   + LNUM*512*NSEQ)
#define OFF_KMIN    (OFF_KMAX + LNUM*512)
#define OFF_Q       (OFF_KMIN + LNUM*512)
#define OFF_AO      (OFF_Q    + LNUM*TTOK*512)
#define OFF_AP      (OFF_AO   + LNUM*TTOK*512)
#define OFF_QF      (OFF_AP   + LNUM*TTOK*512)
#define OFF_GATE    (OFF_QF   + LNUM*TTOK*512)
#define OFF_EXP     (OFF_GATE + LNUM*TTOK)
#define OFF_POS     (OFF_EXP  + LNUM*TTOK)
#define OFF_KEEP    (OFF_POS  + LNUM*TTOK)
#define OFF_BUF     (OFF_KEEP + LNUM*TTOK)          // zeroed region starts here
#define OFF_SSUM    (OFF_BUF  + LNUM*4*CAPE*512)
#define OFF_CNT     (OFF_SSUM + LNUM*4)
#define ZERO_N      (LNUM*4*CAPE*512 + LNUM*4 + LNUM*4)
#define OFF_HEXP    (OFF_CNT  + LNUM*4)
#define OFF_YEXP    (OFF_HEXP + LNUM*4*CAPE*HIDE)
#define OFF_CUR     (OFF_YEXP + LNUM*4*CAPE*512)
#define OFF_Q3      (OFF_CUR  + TTOK*512)
#define OFF_K3      (OFF_Q3   + TTOK*512)
#define OFF_V3      (OFF_K3   + TTOK*512)
#define OFF_AO2     (OFF_V3   + TTOK*512)
#define OFF_XB      (OFF_AO2  + TTOK*512)
#define OFF_HROW    (OFF_XB   + TTOK*512)
#define OFF_HB      (OFF_HROW + TTOK*HIDE)

// ---------------- output layout (floats) ----------------
// logits[2], hazards[2], Y_hat[1], aux[1], feature1[4*64*512], feature2[same], feature2_pre[8]
#define O_F1   6
#define O_F2   (6 + LNUM*TTOK*512)
#define O_F2P  (O_F2 + LNUM*TTOK*512)

__device__ __forceinline__ float wave_sum(float v) {
#pragma unroll
  for (int o = 32; o > 0; o >>= 1) v += __shfl_down(v, o, 64);
  return v;
}

__device__ __forceinline__ float block_sum256(float v) {
  __shared__ float r[4];
  v = wave_sum(v);
  int wid = threadIdx.x >> 6, lane = threadIdx.x & 63;
  if (lane == 0) r[wid] = v;
  __syncthreads();
  float s = r[0] + r[1] + r[2] + r[3];
  __syncthreads();
  return s;
}

// ---------------- K0: zero scratch (buf + ssum + cnt) ----------------
__global__ void k_zero(float* __restrict__ p, int n) {
  int i = blockIdx.x * 256 + threadIdx.x;
  if (i < n) p[i] = 0.f;
}

// ---------------- K1: per-row mu/rstd of share_feature 512-col slices ----------------
__global__ __launch_bounds__(64) void k_rowstats(const float* __restrict__ SF,
                                                 float* __restrict__ mu, float* __restrict__ rstd) {
  int row = blockIdx.x;            // l*4096 + s
  int l = row >> 12, s = row & 4095;
  const float4* x = (const float4*)(SF + (size_t)s * (LNUM * ADIM) + l * ADIM);
  int lane = threadIdx.x;
  float4 a = x[lane], b = x[lane + 64];
  float sum = (a.x + a.y) + (a.z + a.w) + (b.x + b.y) + (b.z + b.w);
  float sq = a.x*a.x + a.y*a.y + a.z*a.z + a.w*a.w + b.x*b.x + b.y*b.y + b.z*b.z + b.w*b.w;
  sum = wave_sum(sum); sq = wave_sum(sq);
  if (lane == 0) {
    float m = sum * (1.f / 512.f);
    float v = sq * (1.f / 512.f) - m * m;
    mu[row] = m; rstd[row] = rsqrtf(v + EPSV);
  }
}

// ---------------- K2: K/V projection GEMM with fused LN; writes K^T, V^T ----------------
// grid (16 n-tiles, 64 m-tiles, L), block 256 (16x16 logical), 64x64x16 tiles, 4x4/thread
__global__ __launch_bounds__(256) void k_kvgemm(const float* __restrict__ SF,
      const float* __restrict__ Wqkv, const float* __restrict__ Bqkv,
      const float* __restrict__ G, const float* __restrict__ Bta,
      const float* __restrict__ mu, const float* __restrict__ rstd,
      float* __restrict__ KT, float* __restrict__ VT) {
  __shared__ float As[16][68], Bs[16][68];
  int l = blockIdx.z;
  int n0 = blockIdx.x * 64, m0 = blockIdx.y * 64;
  int tid = threadIdx.x;
  int tx = tid & 15, ty = tid >> 4;
  int srow = tid >> 2;             // 0..63
  int scol = (tid & 3) * 4;        // 0,4,8,12
  float acc[4][4] = {};
  const float* gL = G + l * ADIM;
  const float* bL = Bta + l * ADIM;
  int m = m0 + srow;
  float mm = mu[l * 4096 + m], rs = rstd[l * 4096 + m];
  const float* wrow = Wqkv + (size_t)l * 1536 * 512 + (size_t)(512 + n0 + srow) * 512;
  for (int k0 = 0; k0 < 512; k0 += 16) {
    float4 av = *(const float4*)(SF + (size_t)m * (LNUM * ADIM) + l * ADIM + k0 + scol);
    float4 gv = *(const float4*)(gL + k0 + scol);
    float4 bv = *(const float4*)(bL + k0 + scol);
    As[scol + 0][srow] = (av.x - mm) * rs * gv.x + bv.x;
    As[scol + 1][srow] = (av.y - mm) * rs * gv.y + bv.y;
    As[scol + 2][srow] = (av.z - mm) * rs * gv.z + bv.z;
    As[scol + 3][srow] = (av.w - mm) * rs * gv.w + bv.w;
    float4 wv = *(const float4*)(wrow + k0 + scol);
    Bs[scol + 0][srow] = wv.x;
    Bs[scol + 1][srow] = wv.y;
    Bs[scol + 2][srow] = wv.z;
    Bs[scol + 3][srow] = wv.w;
    __syncthreads();
#pragma unroll
    for (int kk = 0; kk < 16; kk++) {
      float4 a4 = *(const float4*)&As[kk][ty * 4];
      float4 b4 = *(const float4*)&Bs[kk][tx * 4];
      float a[4] = {a4.x, a4.y, a4.z, a4.w};
      float b[4] = {b4.x, b4.y, b4.z, b4.w};
#pragma unroll
      for (int i = 0; i < 4; i++)
#pragma unroll
        for (int j = 0; j < 4; j++) acc[i][j] = fmaf(a[i], b[j], acc[i][j]);
    }
    __syncthreads();
  }
#pragma unroll
  for (int j = 0; j < 4; j++) {
    int n = n0 + tx * 4 + j;
    float bias = Bqkv[l * 1536 + 512 + n];
    float4 o = make_float4(acc[0][j] + bias, acc[1][j] + bias, acc[2][j] + bias, acc[3][j] + bias);
    float* dst = (n < 512)
        ? (KT + ((size_t)(l * 512 + n)) * 4096 + m0 + ty * 4)
        : (VT + ((size_t)(l * 512 + (n - 512))) * 4096 + m0 + ty * 4);
    *(float4*)dst = o;
  }
}

// ---------------- K3: per-head k min/max ----------------
__global__ __launch_bounds__(256) void k_minmax(const float* __restrict__ KT,
                                                float* __restrict__ kmax, float* __restrict__ kmin) {
  int row = blockIdx.x;            // l*512 + h
  const float4* k = (const float4*)(KT + (size_t)row * 4096);
  float mx = -3.4e38f, mn = 3.4e38f;
  for (int i = threadIdx.x; i < 1024; i += 256) {
    float4 v = k[i];
    mx = fmaxf(mx, fmaxf(fmaxf(v.x, v.y), fmaxf(v.z, v.w)));
    mn = fminf(mn, fminf(fminf(v.x, v.y), fminf(v.z, v.w)));
  }
#pragma unroll
  for (int o = 32; o > 0; o >>= 1) {
    mx = fmaxf(mx, __shfl_down(mx, o, 64));
    mn = fminf(mn, __shfl_down(mn, o, 64));
  }
  __shared__ float rmx[4], rmn[4];
  int wid = threadIdx.x >> 6, lane = threadIdx.x & 63;
  if (lane == 0) { rmx[wid] = mx; rmn[wid] = mn; }
  __syncthreads();
  if (threadIdx.x == 0) {
    kmax[row] = fmaxf(fmaxf(rmx[0], rmx[1]), fmaxf(rmx[2], rmx[3]));
    kmin[row] = fminf(fminf(rmn[0], rmn[1]), fminf(rmn[2], rmn[3]));
  }
}

// ---------------- K4: tok LN + Q projection ----------------
__global__ __launch_bounds__(256) void k_q(const float* __restrict__ TOK,
      const float* __restrict__ G, const float* __restrict__ Bta,
      const float* __restrict__ Wqkv, const float* __restrict__ Bqkv,
      float* __restrict__ Q) {
  int t = blockIdx.x, l = blockIdx.y;
  int tid = threadIdx.x;
  __shared__ float xr[512];
  const float* x = TOK + ((size_t)l * TTOK + t) * ADIM;
  float v0 = x[tid], v1 = x[tid + 256];
  float sum = block_sum256(v0 + v1);
  float sq = block_sum256(v0 * v0 + v1 * v1);
  float m = sum * (1.f / 512.f);
  float rs = rsqrtf(sq * (1.f / 512.f) - m * m + EPSV);
  xr[tid]       = (v0 - m) * rs * G[l * 512 + tid] + Bta[l * 512 + tid];
  xr[tid + 256] = (v1 - m) * rs * G[l * 512 + tid + 256] + Bta[l * 512 + tid + 256];
  __syncthreads();
#pragma unroll
  for (int rep = 0; rep < 2; rep++) {
    int h = rep * 256 + tid;
    const float4* w = (const float4*)(Wqkv + (size_t)l * 1536 * 512 + (size_t)h * 512);
    float acc = 0.f;
#pragma unroll 8
    for (int c = 0; c < 128; c++) {
      float4 wv = w[c]; float4 xv = ((const float4*)xr)[c];
      acc = fmaf(wv.x, xv.x, acc); acc = fmaf(wv.y, xv.y, acc);
      acc = fmaf(wv.z, xv.z, acc); acc = fmaf(wv.w, xv.w, acc);
    }
    Q[((size_t)l * TTOK + t) * 512 + h] = acc + Bqkv[l * 1536 + h];
  }
}

// ---------------- K5: hd=1 attention, one block per (head, layer) ----------------
__global__ __launch_bounds__(256) void k_attn(const float* __restrict__ KT, const float* __restrict__ VT,
      const float* __restrict__ Q, const float* __restrict__ kmax, const float* __restrict__ kmin,
      float* __restrict__ AO) {
  int h = blockIdx.x, l = blockIdx.y;
  __shared__ float kk[4096], vv[4096];
  __shared__ float pden[4][64], pnum[4][64];
  const float4* kp = (const float4*)(KT + ((size_t)(l * 512 + h)) * 4096);
  const float4* vp = (const float4*)(VT + ((size_t)(l * 512 + h)) * 4096);
  for (int i = threadIdx.x; i < 1024; i += 256) {
    ((float4*)kk)[i] = kp[i];
    ((float4*)vv)[i] = vp[i];
  }
  __syncthreads();
  int w = threadIdx.x >> 6, lane = threadIdx.x & 63;
  float q = Q[((size_t)l * TTOK + lane) * 512 + h];
  float km = kmax[l * 512 + h], kn = kmin[l * 512 + h];
  float m = (q >= 0.f) ? q * km : q * kn;     // exact softmax max (hd=1)
  float den = 0.f, num = 0.f;
  int s0 = w * 1024;
#pragma unroll 4
  for (int s = s0; s < s0 + 1024; s++) {
    float e = __expf(fmaf(q, kk[s], -m));
    den += e;
    num = fmaf(e, vv[s], num);
  }
  pden[w][lane] = den; pnum[w][lane] = num;
  __syncthreads();
  if (w == 0) {
    float d = pden[0][lane] + pden[1][lane] + pden[2][lane] + pden[3][lane];
    float n = pnum[0][lane] + pnum[1][lane] + pnum[2][lane] + pnum[3][lane];
    AO[((size_t)l * TTOK + lane) * 512 + h] = n / d;
  }
}

// ---------------- K6: generic row GEMM (64-row in, 512 out, K=512), opt residual ----------------
__global__ __launch_bounds__(256) void k_rowgemm512(const float* __restrict__ IN,
      const float* __restrict__ W, const float* __restrict__ B, const float* __restrict__ RES,
      float* __restrict__ OUT, unsigned long long wsl, int bsl) {
  int t = blockIdx.x, l = blockIdx.y;
  int row = l * gridDim.x + t;
  int tid = threadIdx.x;
  __shared__ float xr[512];
  xr[tid] = IN[(size_t)row * 512 + tid];
  xr[tid + 256] = IN[(size_t)row * 512 + 256 + tid];
  __syncthreads();
#pragma unroll
  for (int rep = 0; rep < 2; rep++) {
    int h = rep * 256 + tid;
    const float4* w = (const float4*)(W + (size_t)l * wsl + (size_t)h * 512);
    float acc = 0.f;
#pragma unroll 8
    for (int c = 0; c < 128; c++) {
      float4 wv = w[c]; float4 xv = ((const float4*)xr)[c];
      acc = fmaf(wv.x, xv.x, acc); acc = fmaf(wv.y, xv.y, acc);
      acc = fmaf(wv.z, xv.z, acc); acc = fmaf(wv.w, xv.w, acc);
    }
    float o = acc + B[l * bsl + h];
    if (RES) o += RES[(size_t)row * 512 + h];
    OUT[(size_t)row * 512 + h] = o;
  }
}

// ---------------- K7a: MoE gating (p-proj, norm, logits, softmax, argmax) ----------------
__global__ __launch_bounds__(256) void k_gate(const float* __restrict__ QF,
      const float* __restrict__ PW, const float* __restrict__ SIM, const float* __restrict__ TEMP,
      float* __restrict__ gate, int* __restrict__ expert,
      float* __restrict__ ssum, int* __restrict__ cnt) {
  int t = blockIdx.x, l = blockIdx.y;
  int tid = threadIdx.x;
  __shared__ float xr[512];
  __shared__ float sp[256];
  __shared__ float lg[4];
  const float* x = QF + ((size_t)l * TTOK + t) * 512;
  xr[tid] = x[tid]; xr[tid + 256] = x[tid + 256];
  __syncthreads();
  float p = 0.f;
  for (int c = 0; c < 512; c++) p = fmaf(xr[c], PW[c * 256 + tid], p);
  float nrm = block_sum256(p * p);
  float pn = p / (sqrtf(nrm) + 1e-8f);
  sp[tid] = pn;
  __syncthreads();
  if (tid < 4) {
    float ls = 0.f, ns = 0.f;
    for (int j = 0; j < 256; j++) {
      float sv = SIM[j * 4 + tid];
      ls = fmaf(sp[j], sv, ls);
      ns = fmaf(sv, sv, ns);
    }
    float scale = __expf(fminf(TEMP[0], 4.6051701859880914f));  // min(temp, log 100)
    lg[tid] = ls / (sqrtf(ns) + 1e-8f) * scale;
  }
  __syncthreads();
  if (tid == 0) {
    float l0 = lg[0], l1 = lg[1], l2 = lg[2], l3 = lg[3];
    int best = 0; float bv = l0;
    if (l1 > bv) { best = 1; bv = l1; }
    if (l2 > bv) { best = 2; bv = l2; }
    if (l3 > bv) { best = 3; bv = l3; }
    float mx = fmaxf(fmaxf(l0, l1), fmaxf(l2, l3));
    float e0 = __expf(l0 - mx), e1 = __expf(l1 - mx), e2 = __expf(l2 - mx), e3 = __expf(l3 - mx);
    float inv = 1.f / (e0 + e1 + e2 + e3);
    float s0 = e0 * inv, s1 = e1 * inv, s2 = e2 * inv, s3 = e3 * inv;
    float sb = (best == 0) ? s0 : (best == 1) ? s1 : (best == 2) ? s2 : s3;
    gate[l * TTOK + t] = sb;
    expert[l * TTOK + t] = best;
    atomicAdd(&ssum[l * 4 + 0], s0); atomicAdd(&ssum[l * 4 + 1], s1);
    atomicAdd(&ssum[l * 4 + 2], s2); atomicAdd(&ssum[l * 4 + 3], s3);
    atomicAdd(&cnt[l * 4 + best], 1);
  }
}

// ---------------- K7b: capacity routing (stable descending sort rank) ----------------
__global__ __launch_bounds__(64) void k_route(const float* __restrict__ gate, const int* __restrict__ expert,
                                              int* __restrict__ pos, int* __restrict__ keep) {
  int l = blockIdx.x;
  int t = threadIdx.x;
  __shared__ float g[64];
  __shared__ int e[64];
  g[t] = gate[l * TTOK + t]; e[t] = expert[l * TTOK + t];
  __syncthreads();
  float gt = g[t]; int et = e[t];
  int p = 0;
  for (int u = 0; u < 64; u++)
    if (e[u] == et && (g[u] > gt || (g[u] == gt && u < t))) p++;
  pos[l * TTOK + t] = p;
  keep[l * TTOK + t] = (p < CAPE) ? 1 : 0;
}

// ---------------- K7c: scatter kept tokens into expert buffers ----------------
__global__ __launch_bounds__(128) void k_scatter(const float* __restrict__ QF, const int* __restrict__ expert,
      const int* __restrict__ pos, const int* __restrict__ keep, float* __restrict__ buf) {
  int t = blockIdx.x, l = blockIdx.y;
  int idx = l * TTOK + t;
  if (!keep[idx]) return;
  int e = expert[idx], p = pos[idx];
  const float4* src = (const float4*)(QF + ((size_t)l * TTOK + t) * 512);
  float4* dst = (float4*)(buf + (((size_t)(l * 4 + e)) * CAPE + p) * 512);
  dst[threadIdx.x] = src[threadIdx.x];
}

// ---------------- K8a: expert up-proj + exact gelu ----------------
__global__ __launch_bounds__(256) void k_moe_h(const float* __restrict__ buf, const float* __restrict__ W1,
      const float* __restrict__ B1, float* __restrict__ H) {
  int le = blockIdx.y;             // l*4 + e
  int e = le & 3;
  int col = blockIdx.x * 256 + threadIdx.x;
  __shared__ float sb[16 * 512];
  const float4* bp = (const float4*)(buf + (size_t)le * 16 * 512);
  for (int i = threadIdx.x; i < 2048; i += 256) ((float4*)sb)[i] = bp[i];
  __syncthreads();
  float acc[16];
  float bias = B1[e * HIDE + col];
#pragma unroll
  for (int c = 0; c < 16; c++) acc[c] = bias;
  const float* w = W1 + (size_t)e * 512 * HIDE + col;
  for (int d = 0; d < 512; d++) {
    float wv = w[(size_t)d * HIDE];
#pragma unroll
    for (int c = 0; c < 16; c++) acc[c] = fmaf(sb[c * 512 + d], wv, acc[c]);
  }
  float* outp = H + (size_t)le * 16 * HIDE + col;
#pragma unroll
  for (int c = 0; c < 16; c++) {
    float v = acc[c];
    outp[(size_t)c * HIDE] = 0.5f * v * (1.f + erff(v * 0.70710678118654752f));
  }
}

// ---------------- K8b: expert down-proj ----------------
__global__ __launch_bounds__(256) void k_moe_y(const float* __restrict__ H, const float* __restrict__ W2,
      const float* __restrict__ B2, float* __restrict__ Y) {
  int le = blockIdx.y;
  int e = le & 3;
  int tx = threadIdx.x & 63, ty = threadIdx.x >> 6;
  int col = blockIdx.x * 64 + tx;
  __shared__ float sh[16 * 512];
  float acc[4];
  float bias = B2[e * 512 + col];
#pragma unroll
  for (int r = 0; r < 4; r++) acc[r] = bias;
  const float4* hp = (const float4*)(H + (size_t)le * 16 * HIDE);
  for (int k0 = 0; k0 < HIDE; k0 += 512) {
    for (int i = threadIdx.x; i < 2048; i += 256) {
      int c = i >> 7, kk4 = i & 127;
      ((float4*)(sh + c * 512))[kk4] = hp[(size_t)c * 512 + (k0 >> 2) + kk4];
    }
    __syncthreads();
    const float* w = W2 + (size_t)e * HIDE * 512 + (size_t)k0 * 512 + col;
    for (int k = 0; k < 512; k++) {
      float wv = w[(size_t)k * 512];
#pragma unroll
      for (int r = 0; r < 4; r++) acc[r] = fmaf(sh[(ty * 4 + r) * 512 + k], wv, acc[r]);
    }
    __syncthreads();
  }
#pragma unroll
  for (int r = 0; r < 4; r++) Y[(size_t)le * 16 * 512 + (size_t)(ty * 4 + r) * 512 + col] = acc[r];
}

// ---------------- K9: gather expert outputs, prefix over layers, write feature1/feature2, cur ----------------
__global__ __launch_bounds__(512) void k_combine(const float* __restrict__ Y, const int* __restrict__ expert,
      const int* __restrict__ pos, const int* __restrict__ keep, const float* __restrict__ gate,
      float* __restrict__ f1, float* __restrict__ f2, float* __restrict__ cur) {
  int t = blockIdx.x;
  int d = threadIdx.x;
  float acc = 0.f;
#pragma unroll
  for (int l = 0; l < LNUM; l++) {
    int idx = l * TTOK + t;
    float v = 0.f;
    if (keep[idx]) {
      int e = expert[idx], p = pos[idx];
      v = Y[(((size_t)(l * 4 + e)) * CAPE + p) * 512 + d] * gate[idx];
    }
    acc += v;
    f1[((size_t)l * TTOK + t) * 512 + d] = acc;
    f2[((size_t)l * TTOK + t) * 512 + d] = 0.f;
  }
  cur[(size_t)t * 512 + d] = acc * 0.25f;
}

// ---------------- K10: GSA LN1 + qkv ----------------
__global__ __launch_bounds__(256) void k_gsa_qkv(const float* __restrict__ CUR,
      const float* __restrict__ G, const float* __restrict__ Bta,
      const float* __restrict__ W, const float* __restrict__ B,
      float* __restrict__ Q3, float* __restrict__ K3, float* __restrict__ V3) {
  int t = blockIdx.x;
  int tid = threadIdx.x;
  __shared__ float xr[512];
  const float* x = CUR + (size_t)t * 512;
  float v0 = x[tid], v1 = x[tid + 256];
  float sum = block_sum256(v0 + v1);
  float sq = block_sum256(v0 * v0 + v1 * v1);
  float m = sum * (1.f / 512.f);
  float rs = rsqrtf(sq * (1.f / 512.f) - m * m + EPSV);
  xr[tid] = (v0 - m) * rs * G[tid] + Bta[tid];
  xr[tid + 256] = (v1 - m) * rs * G[tid + 256] + Bta[tid + 256];
  __syncthreads();
  for (int rep = 0; rep < 6; rep++) {
    int h = rep * 256 + tid;
    const float4* w = (const float4*)(W + (size_t)h * 512);
    float acc = 0.f;
#pragma unroll 8
    for (int c = 0; c < 128; c++) {
      float4 wv = w[c]; float4 xv = ((const float4*)xr)[c];
      acc = fmaf(wv.x, xv.x, acc); acc = fmaf(wv.y, xv.y, acc);
      acc = fmaf(wv.z, xv.z, acc); acc = fmaf(wv.w, xv.w, acc);
    }
    float o = acc + B[h];
    if (h < 512) Q3[(size_t)t * 512 + h] = o;
    else if (h < 1024) K3[(size_t)t * 512 + (h - 512)] = o;
    else V3[(size_t)t * 512 + (h - 1024)] = o;
  }
}

// ---------------- K11: GSA attention (8 heads, hd=64) ----------------
__global__ __launch_bounds__(64) void k_gsa_attn(const float* __restrict__ Q3, const float* __restrict__ K3,
      const float* __restrict__ V3, float* __restrict__ AO2) {
  int h = blockIdx.x;
  int t = threadIdx.x;
  __shared__ float kh[64][65], vh[64][65], ph[64][65];
  float q[64];
  const float4* qp = (const float4*)(Q3 + (size_t)t * 512 + h * 64);
  const float4* kp = (const float4*)(K3 + (size_t)t * 512 + h * 64);
  const float4* vp = (const float4*)(V3 + (size_t)t * 512 + h * 64);
#pragma unroll
  for (int i = 0; i < 16; i++) {
    float4 v = qp[i]; q[4 * i] = v.x; q[4 * i + 1] = v.y; q[4 * i + 2] = v.z; q[4 * i + 3] = v.w;
    float4 kv = kp[i]; kh[t][4 * i] = kv.x; kh[t][4 * i + 1] = kv.y; kh[t][4 * i + 2] = kv.z; kh[t][4 * i + 3] = kv.w;
    float4 vv = vp[i]; vh[t][4 * i] = vv.x; vh[t][4 * i + 1] = vv.y; vh[t][4 * i + 2] = vv.z; vh[t][4 * i + 3] = vv.w;
  }
  __syncthreads();
  float m = -3.4e38f;
  for (int s = 0; s < 64; s++) {
    float acc = 0.f;
#pragma unroll
    for (int d = 0; d < 64; d++) acc = fmaf(q[d], kh[s][d], acc);
    acc *= 0.125f;                 // 1/sqrt(64)
    ph[t][s] = acc;
    m = fmaxf(m, acc);
  }
  float den = 0.f;
  for (int s = 0; s < 64; s++) { float e = __expf(ph[t][s] - m); ph[t][s] = e; den += e; }
  float inv = 1.f / den;
  for (int d = 0; d < 64; d++) {
    float acc = 0.f;
#pragma unroll
    for (int s = 0; s < 64; s++) acc = fmaf(ph[t][s], vh[s][d], acc);
    AO2[(size_t)t * 512 + h * 64 + d] = acc * inv;
  }
}

// ---------------- K13: GSA LN2 + fc + swish ----------------
__global__ __launch_bounds__(256) void k_gsa_fc(const float* __restrict__ XB,
      const float* __restrict__ G, const float* __restrict__ Bta,
      const float* __restrict__ W, const float* __restrict__ B, float* __restrict__ H) {
  int t = blockIdx.x;
  int tid = threadIdx.x;
  __shared__ float xr[512];
  const float* x = XB + (size_t)t * 512;
  float v0 = x[tid], v1 = x[tid + 256];
  float sum = block_sum256(v0 + v1);
  float sq = block_sum256(v0 * v0 + v1 * v1);
  float m = sum * (1.f / 512.f);
  float rs = rsqrtf(sq * (1.f / 512.f) - m * m + EPSV);
  xr[tid] = (v0 - m) * rs * G[tid] + Bta[tid];
  xr[tid + 256] = (v1 - m) * rs * G[tid + 256] + Bta[tid + 256];
  __syncthreads();
  for (int rep = 0; rep < 8; rep++) {
    int o = rep * 256 + tid;
    const float4* w = (const float4*)(W + (size_t)o * 512);
    float acc = 0.f;
#pragma unroll 8
    for (int c = 0; c < 128; c++) {
      float4 wv = w[c]; float4 xv = ((const float4*)xr)[c];
      acc = fmaf(wv.x, xv.x, acc); acc = fmaf(wv.y, xv.y, acc);
      acc = fmaf(wv.z, xv.z, acc); acc = fmaf(wv.w, xv.w, acc);
    }
    acc += B[o];
    H[(size_t)t * HIDE + o] = acc / (1.f + __expf(-1.702f * acc));
  }
}

// ---------------- K14: gated = x + h@proj.T + b; hb = gated@butter.T + b ----------------
__global__ __launch_bounds__(256) void k_gsa_proj(const float* __restrict__ XB, const float* __restrict__ HROW,
      const float* __restrict__ PW, const float* __restrict__ PB,
      const float* __restrict__ BW, const float* __restrict__ BB, float* __restrict__ HB) {
  int t = blockIdx.x;
  int tid = threadIdx.x;
  __shared__ float hr[2048];
  __shared__ float gr[512];
  const float4* hp = (const float4*)(HROW + (size_t)t * HIDE);
  for (int i = tid; i < 512; i += 256) ((float4*)hr)[i] = hp[i];
  __syncthreads();
#pragma unroll
  for (int rep = 0; rep < 2; rep++) {
    int o = rep * 256 + tid;
    const float4* w = (const float4*)(PW + (size_t)o * HIDE);
    float acc = 0.f;
#pragma unroll 4
    for (int c = 0; c < 512; c++) {
      float4 wv = w[c]; float4 xv = ((const float4*)hr)[c];
      acc = fmaf(wv.x, xv.x, acc); acc = fmaf(wv.y, xv.y, acc);
      acc = fmaf(wv.z, xv.z, acc); acc = fmaf(wv.w, xv.w, acc);
    }
    gr[o] = acc + PB[o] + XB[(size_t)t * 512 + o];
  }
  __syncthreads();
  {
    int j = tid;
    const float4* w = (const float4*)(BW + (size_t)j * 512);
    float acc = 0.f;
#pragma unroll 8
    for (int c = 0; c < 128; c++) {
      float4 wv = w[c]; float4 xv = ((const float4*)gr)[c];
      acc = fmaf(wv.x, xv.x, acc); acc = fmaf(wv.y, xv.y, acc);
      acc = fmaf(wv.z, xv.z, acc); acc = fmaf(wv.w, xv.w, acc);
    }
    HB[(size_t)t * 256 + j] = acc + BB[j];
  }
}

// ---------------- K15: classifier head + hazards + Y_hat + aux + feature2_pre ----------------
__global__ __launch_bounds__(256) void k_final(const float* __restrict__ HB,
      const float* __restrict__ CW, const float* __restrict__ CB,
      const float* __restrict__ ssum, const int* __restrict__ cnt,
      float* __restrict__ out) {
  int tid = threadIdx.x;
  float p0 = 0.f, p1 = 0.f;
  for (int i = tid; i < 16384; i += 256) {
    float h = HB[i];
    p0 = fmaf(h, CW[i], p0);
    p1 = fmaf(h, CW[16384 + i], p1);
  }
  p0 = block_sum256(p0);
  p1 = block_sum256(p1);
  if (tid == 0) {
    float l0 = p0 + CB[0], l1 = p1 + CB[1];
    out[0] = l0; out[1] = l1;
    out[2] = 1.f / (1.f + __expf(-l0));
    out[3] = 1.f / (1.f + __expf(-l1));
    out[4] = (l1 > l0) ? 1.f : 0.f;   // argmax, first max on ties
    float aux = 0.f;
    for (int i = 0; i < 16; i++) aux += (ssum[i] * (1.f / 64.f)) * ((float)cnt[i] * (1.f / 64.f));
    out[5] = aux * 4.f * 0.01f;       // * E * AUX_W
  }
  if (tid < 8) out[O_F2P + tid] = 0.f;
}

extern "C" void kernel_launch(void* const* d_in, const int* in_sizes, int n_in,
                              void* d_out, int out_size, void* d_ws, size_t ws_size,
                              hipStream_t stream) {
  const float* SF    = (const float*)d_in[0];
  const float* TOK   = (const float*)d_in[1];
  const float* LN1G  = (const float*)d_in[2];
  const float* LN1B  = (const float*)d_in[3];
  const float* LN2G  = (const float*)d_in[4];
  const float* LN2B  = (const float*)d_in[5];
  const float* QKVW  = (const float*)d_in[6];
  const float* QKVB  = (const float*)d_in[7];
  const float* OUTW  = (const float*)d_in[8];
  const float* OUTB  = (const float*)d_in[9];
  const float* MLPW  = (const float*)d_in[10];
  const float* MLPB  = (const float*)d_in[11];
  const float* GPW   = (const float*)d_in[12];
  const float* GSIM  = (const float*)d_in[13];
  const float* GTMP  = (const float*)d_in[14];
  const float* EW1   = (const float*)d_in[15];
  const float* EB1   = (const float*)d_in[16];
  const float* EW2   = (const float*)d_in[17];
  const float* EB2   = (const float*)d_in[18];
  const float* GL1G  = (const float*)d_in[19];
  const float* GL1B  = (const float*)d_in[20];
  const float* GQKVW = (const float*)d_in[21];
  const float* GQKVB = (const float*)d_in[22];
  const float* GOUTW = (const float*)d_in[23];
  const float* GOUTB = (const float*)d_in[24];
  const float* GL2G  = (const float*)d_in[25];
  const float* GL2B  = (const float*)d_in[26];
  const float* GFCW  = (const float*)d_in[27];
  const float* GFCB  = (const float*)d_in[28];
  const float* GPJW  = (const float*)d_in[29];
  const float* GPJB  = (const float*)d_in[30];
  const float* BTW   = (const float*)d_in[31];
  const float* BTB   = (const float*)d_in[32];
  const float* CLW   = (const float*)d_in[33];
  const float* CLB   = (const float*)d_in[34];

  float* ws  = (float*)d_ws;
  float* out = (float*)d_out;

  float* MU   = ws + OFF_MU;
  float* RSTD = ws + OFF_RSTD;
  float* KT   = ws + OFF_KT;
  float* VT   = ws + OFF_VT;
  float* KMAX = ws + OFF_KMAX;
  float* KMIN = ws + OFF_KMIN;
  float* Q    = ws + OFF_Q;
  float* AO   = ws + OFF_AO;
  float* AP   = ws + OFF_AP;
  float* QF   = ws + OFF_QF;
  float* GATE = ws + OFF_GATE;
  int*   EXPI = (int*)(ws + OFF_EXP);
  int*   POSI = (int*)(ws + OFF_POS);
  int*   KEEPI= (int*)(ws + OFF_KEEP);
  float* BUF  = ws + OFF_BUF;
  float* SSUM = ws + OFF_SSUM;
  int*   CNT  = (int*)(ws + OFF_CNT);
  float* HEXP = ws + OFF_HEXP;
  float* YEXP = ws + OFF_YEXP;
  float* CUR  = ws + OFF_CUR;
  float* Q3   = ws + OFF_Q3;
  float* K3   = ws + OFF_K3;
  float* V3   = ws + OFF_V3;
  float* AO2  = ws + OFF_AO2;
  float* XB   = ws + OFF_XB;
  float* HROW = ws + OFF_HROW;
  float* HBB  = ws + OFF_HB;

  k_zero<<<(ZERO_N + 255) / 256, 256, 0, stream>>>(BUF, ZERO_N);
  k_rowstats<<<LNUM * NSEQ, 64, 0, stream>>>(SF, MU, RSTD);
  k_kvgemm<<<dim3(16, 64, LNUM), 256, 0, stream>>>(SF, QKVW, QKVB, LN1G, LN1B, MU, RSTD, KT, VT);
  k_minmax<<<LNUM * 512, 256, 0, stream>>>(KT, KMAX, KMIN);
  k_q<<<dim3(TTOK, LNUM), 256, 0, stream>>>(TOK, LN2G, LN2B, QKVW, QKVB, Q);
  k_attn<<<dim3(512, LNUM), 256, 0, stream>>>(KT, VT, Q, KMAX, KMIN, AO);
  k_rowgemm512<<<dim3(TTOK, LNUM), 256, 0, stream>>>(AO, OUTW, OUTB, nullptr, AP, 512ull * 512ull, 512);
  k_rowgemm512<<<dim3(TTOK, LNUM), 256, 0, stream>>>(AP, MLPW, MLPB, nullptr, QF, 512ull * 512ull, 512);
  k_gate<<<dim3(TTOK, LNUM), 256, 0, stream>>>(QF, GPW, GSIM, GTMP, GATE, EXPI, SSUM, CNT);
  k_route<<<LNUM, 64, 0, stream>>>(GATE, EXPI, POSI, KEEPI);
  k_scatter<<<dim3(TTOK, LNUM), 128, 0, stream>>>(QF, EXPI, POSI, KEEPI, BUF);
  k_moe_h<<<dim3(8, 16), 256, 0, stream>>>(BUF, EW1, EB1, HEXP);
  k_moe_y<<<dim3(8, 16), 256, 0, stream>>>(HEXP, EW2, EB2, YEXP);
  k_combine<<<TTOK, 512, 0, stream>>>(YEXP, EXPI, POSI, KEEPI, GATE, out + O_F1, out + O_F2, CUR);
  k_gsa_qkv<<<TTOK, 256, 0, stream>>>(CUR, GL1G, GL1B, GQKVW, GQKVB, Q3, K3, V3);
  k_gsa_attn<<<8, 64, 0, stream>>>(Q3, K3, V3, AO2);
  k_rowgemm512<<<dim3(TTOK, 1), 256, 0, stream>>>(AO2, GOUTW, GOUTB, CUR, XB, 0ull, 0);
  k_gsa_fc<<<TTOK, 256, 0, stream>>>(XB, GL2G, GL2B, GFCW, GFCB, HROW);
  k_gsa_proj<<<TTOK, 256, 0, stream>>>(XB, HROW, GPJW, GPJB, BTW, BTB, HBB);
  k_final<<<1, 256, 0, stream>>>(HBB, CLW, CLB, SSUM, CNT, out);
}

// Round 2
// 1092.351 us; speedup vs baseline: 1.2304x; 1.2304x over previous
//
#include <hip/hip_runtime.h>
#include <math.h>

// LRENet_2: L=4, AD=D=512, T=64, N=4096, NC=2, PROJ=256, HID=2048, CAP=16
#define LNUM 4
#define ADIM 512
#define TTOK 64
#define NSEQ 4096
#define HIDE 2048
#define CAPE 16
#define EPSV 1e-5f

// ---------------- workspace layout (float offsets) ----------------
#define OFF_MU      0
#define OFF_RSTD    (OFF_MU   + LNUM*NSEQ)
#define OFF_KT      (OFF_RSTD + LNUM*NSEQ)
#define OFF_VT      (OFF_KT   + LNUM*512*NSEQ)
#define OFF_KMAX    (OFF_VT   + LNUM*512*NSEQ)
#define OFF_KMIN    (OFF_KMAX + LNUM*512)
#define OFF_Q       (OFF_KMIN + LNUM*512)
#define OFF_AO      (OFF_Q    + LNUM*TTOK*512)
#define OFF_AP      (OFF_AO   + LNUM*TTOK*512)
#define OFF_QF      (OFF_AP   + LNUM*TTOK*512)
#define OFF_GATE    (OFF_QF   + LNUM*TTOK*512)
#define OFF_EXP     (OFF_GATE + LNUM*TTOK)
#define OFF_POS     (OFF_EXP  + LNUM*TTOK)
#define OFF_KEEP    (OFF_POS  + LNUM*TTOK)
#define OFF_BUF     (OFF_KEEP + LNUM*TTOK)          // zeroed region starts here
#define OFF_SSUM    (OFF_BUF  + LNUM*4*CAPE*512)
#define OFF_CNT     (OFF_SSUM + LNUM*4)
#define ZERO_N      (LNUM*4*CAPE*512 + LNUM*4 + LNUM*4)
#define OFF_HEXP    (OFF_CNT  + LNUM*4)
#define OFF_YEXP    (OFF_HEXP + LNUM*4*CAPE*HIDE)
#define OFF_CUR     (OFF_YEXP + LNUM*4*CAPE*512)
#define OFF_Q3      (OFF_CUR  + TTOK*512)
#define OFF_K3      (OFF_Q3   + TTOK*512)
#define OFF_V3      (OFF_K3   + TTOK*512)
#define OFF_AO2     (OFF_V3   + TTOK*512)
#define OFF_XB      (OFF_AO2  + TTOK*512)
#define OFF_HROW    (OFF_XB   + TTOK*512)
#define OFF_HB      (OFF_HROW + TTOK*HIDE)
#define OFF_GATED   (OFF_HB   + TTOK*256)

// ---------------- output layout (floats) ----------------
#define O_F1   6
#define O_F2   (6 + LNUM*TTOK*512)
#define O_F2P  (O_F2 + LNUM*TTOK*512)

__device__ __forceinline__ float wave_sum(float v) {
#pragma unroll
  for (int o = 32; o > 0; o >>= 1) v += __shfl_down(v, o, 64);
  return v;
}

__device__ __forceinline__ float block_sum256(float v) {
  __shared__ float r[4];
  v = wave_sum(v);
  int wid = threadIdx.x >> 6, lane = threadIdx.x & 63;
  if (lane == 0) r[wid] = v;
  __syncthreads();
  float s = r[0] + r[1] + r[2] + r[3];
  __syncthreads();
  return s;
}

// ---------------- K0: zero scratch ----------------
__global__ void k_zero(float* __restrict__ p, int n) {
  int i = blockIdx.x * 256 + threadIdx.x;
  if (i < n) p[i] = 0.f;
}

// ---------------- K1: per-row mu/rstd of share_feature 512-col slices ----------------
__global__ __launch_bounds__(64) void k_rowstats(const float* __restrict__ SF,
                                                 float* __restrict__ mu, float* __restrict__ rstd) {
  int row = blockIdx.x;            // l*4096 + s
  int l = row >> 12, s = row & 4095;
  const float4* x = (const float4*)(SF + (size_t)s * (LNUM * ADIM) + l * ADIM);
  int lane = threadIdx.x;
  float4 a = x[lane], b = x[lane + 64];
  float sum = (a.x + a.y) + (a.z + a.w) + (b.x + b.y) + (b.z + b.w);
  float sq = a.x*a.x + a.y*a.y + a.z*a.z + a.w*a.w + b.x*b.x + b.y*b.y + b.z*b.z + b.w*b.w;
  sum = wave_sum(sum); sq = wave_sum(sq);
  if (lane == 0) {
    float m = sum * (1.f / 512.f);
    float v = sq * (1.f / 512.f) - m * m;
    mu[row] = m; rstd[row] = rsqrtf(v + EPSV);
  }
}

// ---------------- K2: K/V projection GEMM with fused LN; writes K^T, V^T ----------------
// 128x128 tiles, BK=16, 256 threads, 8x8 acc/thread. grid (8 n, 32 m, L)
__global__ __launch_bounds__(256) void k_kvgemm(const float* __restrict__ SF,
      const float* __restrict__ Wqkv, const float* __restrict__ Bqkv,
      const float* __restrict__ G, const float* __restrict__ Bta,
      const float* __restrict__ mu, const float* __restrict__ rstd,
      float* __restrict__ KT, float* __restrict__ VT) {
  __shared__ float As[16][132], Bs[16][132];
  int l = blockIdx.z;
  int n0 = blockIdx.x * 128, m0 = blockIdx.y * 128;
  int tid = threadIdx.x;
  int tx = tid & 15, ty = tid >> 4;
  int srow = tid >> 1;             // 0..127
  int scol = (tid & 1) * 8;        // 0 or 8
  float acc[8][8] = {};
  int m = m0 + srow;
  float mm = mu[l * 4096 + m], rs = rstd[l * 4096 + m];
  const float* aRow = SF + (size_t)m * (LNUM * ADIM) + l * ADIM;
  const float* wRow = Wqkv + (size_t)l * 1536 * 512 + (size_t)(512 + n0 + srow) * 512;
  const float* gL = G + l * ADIM;
  const float* bL = Bta + l * ADIM;
  for (int k0 = 0; k0 < 512; k0 += 16) {
    float4 a0 = *(const float4*)(aRow + k0 + scol);
    float4 a1 = *(const float4*)(aRow + k0 + scol + 4);
    float4 g0 = *(const float4*)(gL + k0 + scol);
    float4 g1 = *(const float4*)(gL + k0 + scol + 4);
    float4 c0 = *(const float4*)(bL + k0 + scol);
    float4 c1 = *(const float4*)(bL + k0 + scol + 4);
    float4 w0 = *(const float4*)(wRow + k0 + scol);
    float4 w1 = *(const float4*)(wRow + k0 + scol + 4);
    As[scol + 0][srow] = (a0.x - mm) * rs * g0.x + c0.x;
    As[scol + 1][srow] = (a0.y - mm) * rs * g0.y + c0.y;
    As[scol + 2][srow] = (a0.z - mm) * rs * g0.z + c0.z;
    As[scol + 3][srow] = (a0.w - mm) * rs * g0.w + c0.w;
    As[scol + 4][srow] = (a1.x - mm) * rs * g1.x + c1.x;
    As[scol + 5][srow] = (a1.y - mm) * rs * g1.y + c1.y;
    As[scol + 6][srow] = (a1.z - mm) * rs * g1.z + c1.z;
    As[scol + 7][srow] = (a1.w - mm) * rs * g1.w + c1.w;
    Bs[scol + 0][srow] = w0.x;
    Bs[scol + 1][srow] = w0.y;
    Bs[scol + 2][srow] = w0.z;
    Bs[scol + 3][srow] = w0.w;
    Bs[scol + 4][srow] = w1.x;
    Bs[scol + 5][srow] = w1.y;
    Bs[scol + 6][srow] = w1.z;
    Bs[scol + 7][srow] = w1.w;
    __syncthreads();
#pragma unroll
    for (int kk = 0; kk < 16; kk++) {
      float a[8], b[8];
      *(float4*)&a[0] = *(const float4*)&As[kk][ty * 8];
      *(float4*)&a[4] = *(const float4*)&As[kk][ty * 8 + 4];
      *(float4*)&b[0] = *(const float4*)&Bs[kk][tx * 8];
      *(float4*)&b[4] = *(const float4*)&Bs[kk][tx * 8 + 4];
#pragma unroll
      for (int i = 0; i < 8; i++)
#pragma unroll
        for (int j = 0; j < 8; j++) acc[i][j] = fmaf(a[i], b[j], acc[i][j]);
    }
    __syncthreads();
  }
#pragma unroll
  for (int j = 0; j < 8; j++) {
    int n = n0 + tx * 8 + j;
    float bias = Bqkv[l * 1536 + 512 + n];
    float* base = (n < 512) ? (KT + ((size_t)(l * 512 + n)) * 4096)
                            : (VT + ((size_t)(l * 512 + (n - 512))) * 4096);
    float4 o0 = make_float4(acc[0][j] + bias, acc[1][j] + bias, acc[2][j] + bias, acc[3][j] + bias);
    float4 o1 = make_float4(acc[4][j] + bias, acc[5][j] + bias, acc[6][j] + bias, acc[7][j] + bias);
    *(float4*)(base + m0 + ty * 8) = o0;
    *(float4*)(base + m0 + ty * 8 + 4) = o1;
  }
}

// ---------------- K3: per-head k min/max ----------------
__global__ __launch_bounds__(256) void k_minmax(const float* __restrict__ KT,
                                                float* __restrict__ kmax, float* __restrict__ kmin) {
  int row = blockIdx.x;            // l*512 + h
  const float4* k = (const float4*)(KT + (size_t)row * 4096);
  float mx = -3.4e38f, mn = 3.4e38f;
  for (int i = threadIdx.x; i < 1024; i += 256) {
    float4 v = k[i];
    mx = fmaxf(mx, fmaxf(fmaxf(v.x, v.y), fmaxf(v.z, v.w)));
    mn = fminf(mn, fminf(fminf(v.x, v.y), fminf(v.z, v.w)));
  }
#pragma unroll
  for (int o = 32; o > 0; o >>= 1) {
    mx = fmaxf(mx, __shfl_down(mx, o, 64));
    mn = fminf(mn, __shfl_down(mn, o, 64));
  }
  __shared__ float rmx[4], rmn[4];
  int wid = threadIdx.x >> 6, lane = threadIdx.x & 63;
  if (lane == 0) { rmx[wid] = mx; rmn[wid] = mn; }
  __syncthreads();
  if (threadIdx.x == 0) {
    kmax[row] = fmaxf(fmaxf(rmx[0], rmx[1]), fmaxf(rmx[2], rmx[3]));
    kmin[row] = fminf(fminf(rmn[0], rmn[1]), fminf(rmn[2], rmn[3]));
  }
}

// ---------------- K4: tok LN + Q projection (z-split halves) ----------------
__global__ __launch_bounds__(256) void k_q(const float* __restrict__ TOK,
      const float* __restrict__ G, const float* __restrict__ Bta,
      const float* __restrict__ Wqkv, const float* __restrict__ Bqkv,
      float* __restrict__ Q) {
  int t = blockIdx.x, l = blockIdx.y;
  int tid = threadIdx.x;
  __shared__ float xr[512];
  const float* x = TOK + ((size_t)l * TTOK + t) * ADIM;
  float v0 = x[tid], v1 = x[tid + 256];
  float sum = block_sum256(v0 + v1);
  float sq = block_sum256(v0 * v0 + v1 * v1);
  float m = sum * (1.f / 512.f);
  float rs = rsqrtf(sq * (1.f / 512.f) - m * m + EPSV);
  xr[tid]       = (v0 - m) * rs * G[l * 512 + tid] + Bta[l * 512 + tid];
  xr[tid + 256] = (v1 - m) * rs * G[l * 512 + tid + 256] + Bta[l * 512 + tid + 256];
  __syncthreads();
  int h = blockIdx.z * 256 + tid;
  const float4* w = (const float4*)(Wqkv + (size_t)l * 1536 * 512 + (size_t)h * 512);
  float acc = 0.f;
#pragma unroll 8
  for (int c = 0; c < 128; c++) {
    float4 wv = w[c]; float4 xv = ((const float4*)xr)[c];
    acc = fmaf(wv.x, xv.x, acc); acc = fmaf(wv.y, xv.y, acc);
    acc = fmaf(wv.z, xv.z, acc); acc = fmaf(wv.w, xv.w, acc);
  }
  Q[((size_t)l * TTOK + t) * 512 + h] = acc + Bqkv[l * 1536 + h];
}

// ---------------- K5: hd=1 attention, one block per (head, layer) ----------------
__global__ __launch_bounds__(256) void k_attn(const float* __restrict__ KT, const float* __restrict__ VT,
      const float* __restrict__ Q, const float* __restrict__ kmax, const float* __restrict__ kmin,
      float* __restrict__ AO) {
  int h = blockIdx.x, l = blockIdx.y;
  __shared__ float kk[4096], vv[4096];
  __shared__ float pden[4][64], pnum[4][64];
  const float4* kp = (const float4*)(KT + ((size_t)(l * 512 + h)) * 4096);
  const float4* vp = (const float4*)(VT + ((size_t)(l * 512 + h)) * 4096);
  for (int i = threadIdx.x; i < 1024; i += 256) {
    ((float4*)kk)[i] = kp[i];
    ((float4*)vv)[i] = vp[i];
  }
  __syncthreads();
  int w = threadIdx.x >> 6, lane = threadIdx.x & 63;
  float q = Q[((size_t)l * TTOK + lane) * 512 + h];
  float km = kmax[l * 512 + h], kn = kmin[l * 512 + h];
  float m = (q >= 0.f) ? q * km : q * kn;     // exact softmax max (hd=1)
  float den = 0.f, num = 0.f;
  int s0 = w * 1024;
#pragma unroll 4
  for (int s = s0; s < s0 + 1024; s++) {
    float e = __expf(fmaf(q, kk[s], -m));
    den += e;
    num = fmaf(e, vv[s], num);
  }
  pden[w][lane] = den; pnum[w][lane] = num;
  __syncthreads();
  if (w == 0) {
    float d = pden[0][lane] + pden[1][lane] + pden[2][lane] + pden[3][lane];
    float n = pnum[0][lane] + pnum[1][lane] + pnum[2][lane] + pnum[3][lane];
    AO[((size_t)l * TTOK + lane) * 512 + h] = n / d;
  }
}

// ---------------- K6: generic row GEMM (64-row in, 512 out, K=512), z-split, opt residual ----------------
__global__ __launch_bounds__(256) void k_rowgemm512(const float* __restrict__ IN,
      const float* __restrict__ W, const float* __restrict__ B, const float* __restrict__ RES,
      float* __restrict__ OUT, unsigned long long wsl, int bsl) {
  int t = blockIdx.x, l = blockIdx.y;
  int row = l * gridDim.x + t;
  int tid = threadIdx.x;
  __shared__ float xr[512];
  xr[tid] = IN[(size_t)row * 512 + tid];
  xr[tid + 256] = IN[(size_t)row * 512 + 256 + tid];
  __syncthreads();
  int h = blockIdx.z * 256 + tid;
  const float4* w = (const float4*)(W + (size_t)l * wsl + (size_t)h * 512);
  float acc = 0.f;
#pragma unroll 8
  for (int c = 0; c < 128; c++) {
    float4 wv = w[c]; float4 xv = ((const float4*)xr)[c];
    acc = fmaf(wv.x, xv.x, acc); acc = fmaf(wv.y, xv.y, acc);
    acc = fmaf(wv.z, xv.z, acc); acc = fmaf(wv.w, xv.w, acc);
  }
  float o = acc + B[l * bsl + h];
  if (RES) o += RES[(size_t)row * 512 + h];
  OUT[(size_t)row * 512 + h] = o;
}

// ---------------- K7a: MoE gating ----------------
__global__ __launch_bounds__(256) void k_gate(const float* __restrict__ QF,
      const float* __restrict__ PW, const float* __restrict__ SIM, const float* __restrict__ TEMP,
      float* __restrict__ gate, int* __restrict__ expert,
      float* __restrict__ ssum, int* __restrict__ cnt) {
  int t = blockIdx.x, l = blockIdx.y;
  int tid = threadIdx.x;
  __shared__ float xr[512];
  __shared__ float sp[256];
  __shared__ float lg[4];
  const float* x = QF + ((size_t)l * TTOK + t) * 512;
  xr[tid] = x[tid]; xr[tid + 256] = x[tid + 256];
  __syncthreads();
  float p = 0.f;
  for (int c = 0; c < 512; c++) p = fmaf(xr[c], PW[c * 256 + tid], p);
  float nrm = block_sum256(p * p);
  float pn = p / (sqrtf(nrm) + 1e-8f);
  sp[tid] = pn;
  __syncthreads();
  if (tid < 4) {
    float ls = 0.f, ns = 0.f;
    for (int j = 0; j < 256; j++) {
      float sv = SIM[j * 4 + tid];
      ls = fmaf(sp[j], sv, ls);
      ns = fmaf(sv, sv, ns);
    }
    float scale = __expf(fminf(TEMP[0], 4.6051701859880914f));  // min(temp, log 100)
    lg[tid] = ls / (sqrtf(ns) + 1e-8f) * scale;
  }
  __syncthreads();
  if (tid == 0) {
    float l0 = lg[0], l1 = lg[1], l2 = lg[2], l3 = lg[3];
    int best = 0; float bv = l0;
    if (l1 > bv) { best = 1; bv = l1; }
    if (l2 > bv) { best = 2; bv = l2; }
    if (l3 > bv) { best = 3; bv = l3; }
    float mx = fmaxf(fmaxf(l0, l1), fmaxf(l2, l3));
    float e0 = __expf(l0 - mx), e1 = __expf(l1 - mx), e2 = __expf(l2 - mx), e3 = __expf(l3 - mx);
    float inv = 1.f / (e0 + e1 + e2 + e3);
    float s0 = e0 * inv, s1 = e1 * inv, s2 = e2 * inv, s3 = e3 * inv;
    float sb = (best == 0) ? s0 : (best == 1) ? s1 : (best == 2) ? s2 : s3;
    gate[l * TTOK + t] = sb;
    expert[l * TTOK + t] = best;
    atomicAdd(&ssum[l * 4 + 0], s0); atomicAdd(&ssum[l * 4 + 1], s1);
    atomicAdd(&ssum[l * 4 + 2], s2); atomicAdd(&ssum[l * 4 + 3], s3);
    atomicAdd(&cnt[l * 4 + best], 1);
  }
}

// ---------------- K7b: capacity routing ----------------
__global__ __launch_bounds__(64) void k_route(const float* __restrict__ gate, const int* __restrict__ expert,
                                              int* __restrict__ pos, int* __restrict__ keep) {
  int l = blockIdx.x;
  int t = threadIdx.x;
  __shared__ float g[64];
  __shared__ int e[64];
  g[t] = gate[l * TTOK + t]; e[t] = expert[l * TTOK + t];
  __syncthreads();
  float gt = g[t]; int et = e[t];
  int p = 0;
  for (int u = 0; u < 64; u++)
    if (e[u] == et && (g[u] > gt || (g[u] == gt && u < t))) p++;
  pos[l * TTOK + t] = p;
  keep[l * TTOK + t] = (p < CAPE) ? 1 : 0;
}

// ---------------- K7c: scatter kept tokens into expert buffers ----------------
__global__ __launch_bounds__(128) void k_scatter(const float* __restrict__ QF, const int* __restrict__ expert,
      const int* __restrict__ pos, const int* __restrict__ keep, float* __restrict__ buf) {
  int t = blockIdx.x, l = blockIdx.y;
  int idx = l * TTOK + t;
  if (!keep[idx]) return;
  int e = expert[idx], p = pos[idx];
  const float4* src = (const float4*)(QF + ((size_t)l * TTOK + t) * 512);
  float4* dst = (float4*)(buf + (((size_t)(l * 4 + e)) * CAPE + p) * 512);
  dst[threadIdx.x] = src[threadIdx.x];
}

// ---------------- K8a: expert up-proj + exact gelu ----------------
__global__ __launch_bounds__(256) void k_moe_h(const float* __restrict__ buf, const float* __restrict__ W1,
      const float* __restrict__ B1, float* __restrict__ H) {
  int le = blockIdx.y;             // l*4 + e
  int e = le & 3;
  int col = blockIdx.x * 256 + threadIdx.x;
  __shared__ float sb[16 * 512];
  const float4* bp = (const float4*)(buf + (size_t)le * 16 * 512);
  for (int i = threadIdx.x; i < 2048; i += 256) ((float4*)sb)[i] = bp[i];
  __syncthreads();
  float acc[16];
  float bias = B1[e * HIDE + col];
#pragma unroll
  for (int c = 0; c < 16; c++) acc[c] = bias;
  const float* w = W1 + (size_t)e * 512 * HIDE + col;
  for (int d = 0; d < 512; d++) {
    float wv = w[(size_t)d * HIDE];
#pragma unroll
    for (int c = 0; c < 16; c++) acc[c] = fmaf(sb[c * 512 + d], wv, acc[c]);
  }
  float* outp = H + (size_t)le * 16 * HIDE + col;
#pragma unroll
  for (int c = 0; c < 16; c++) {
    float v = acc[c];
    outp[(size_t)c * HIDE] = 0.5f * v * (1.f + erff(v * 0.70710678118654752f));
  }
}

// ---------------- K8b: expert down-proj ----------------
__global__ __launch_bounds__(256) void k_moe_y(const float* __restrict__ H, const float* __restrict__ W2,
      const float* __restrict__ B2, float* __restrict__ Y) {
  int le = blockIdx.y;
  int e = le & 3;
  int tx = threadIdx.x & 63, ty = threadIdx.x >> 6;
  int col = blockIdx.x * 64 + tx;
  __shared__ float sh[16 * 512];
  float acc[4];
  float bias = B2[e * 512 + col];
#pragma unroll
  for (int r = 0; r < 4; r++) acc[r] = bias;
  const float4* hp = (const float4*)(H + (size_t)le * 16 * HIDE);
  for (int k0 = 0; k0 < HIDE; k0 += 512) {
    for (int i = threadIdx.x; i < 2048; i += 256) {
      int c = i >> 7, kk4 = i & 127;
      ((float4*)(sh + c * 512))[kk4] = hp[(size_t)c * 512 + (k0 >> 2) + kk4];
    }
    __syncthreads();
    const float* w = W2 + (size_t)e * HIDE * 512 + (size_t)k0 * 512 + col;
    for (int k = 0; k < 512; k++) {
      float wv = w[(size_t)k * 512];
#pragma unroll
      for (int r = 0; r < 4; r++) acc[r] = fmaf(sh[(ty * 4 + r) * 512 + k], wv, acc[r]);
    }
    __syncthreads();
  }
#pragma unroll
  for (int r = 0; r < 4; r++) Y[(size_t)le * 16 * 512 + (size_t)(ty * 4 + r) * 512 + col] = acc[r];
}

// ---------------- K9: gather expert outputs, prefix over layers ----------------
__global__ __launch_bounds__(512) void k_combine(const float* __restrict__ Y, const int* __restrict__ expert,
      const int* __restrict__ pos, const int* __restrict__ keep, const float* __restrict__ gate,
      float* __restrict__ f1, float* __restrict__ f2, float* __restrict__ cur) {
  int t = blockIdx.x;
  int d = threadIdx.x;
  float acc = 0.f;
#pragma unroll
  for (int l = 0; l < LNUM; l++) {
    int idx = l * TTOK + t;
    float v = 0.f;
    if (keep[idx]) {
      int e = expert[idx], p = pos[idx];
      v = Y[(((size_t)(l * 4 + e)) * CAPE + p) * 512 + d] * gate[idx];
    }
    acc += v;
    f1[((size_t)l * TTOK + t) * 512 + d] = acc;
    f2[((size_t)l * TTOK + t) * 512 + d] = 0.f;
  }
  cur[(size_t)t * 512 + d] = acc * 0.25f;
}

// ---------------- K10: GSA LN1 + qkv (y = output tile of 256) ----------------
__global__ __launch_bounds__(256) void k_gsa_qkv(const float* __restrict__ CUR,
      const float* __restrict__ G, const float* __restrict__ Bta,
      const float* __restrict__ W, const float* __restrict__ B,
      float* __restrict__ Q3, float* __restrict__ K3, float* __restrict__ V3) {
  int t = blockIdx.x;
  int tid = threadIdx.x;
  __shared__ float xr[512];
  const float* x = CUR + (size_t)t * 512;
  float v0 = x[tid], v1 = x[tid + 256];
  float sum = block_sum256(v0 + v1);
  float sq = block_sum256(v0 * v0 + v1 * v1);
  float m = sum * (1.f / 512.f);
  float rs = rsqrtf(sq * (1.f / 512.f) - m * m + EPSV);
  xr[tid] = (v0 - m) * rs * G[tid] + Bta[tid];
  xr[tid + 256] = (v1 - m) * rs * G[tid + 256] + Bta[tid + 256];
  __syncthreads();
  int h = blockIdx.y * 256 + tid;
  const float4* w = (const float4*)(W + (size_t)h * 512);
  float acc = 0.f;
#pragma unroll 8
  for (int c = 0; c < 128; c++) {
    float4 wv = w[c]; float4 xv = ((const float4*)xr)[c];
    acc = fmaf(wv.x, xv.x, acc); acc = fmaf(wv.y, xv.y, acc);
    acc = fmaf(wv.z, xv.z, acc); acc = fmaf(wv.w, xv.w, acc);
  }
  float o = acc + B[h];
  if (h < 512) Q3[(size_t)t * 512 + h] = o;
  else if (h < 1024) K3[(size_t)t * 512 + (h - 512)] = o;
  else V3[(size_t)t * 512 + (h - 1024)] = o;
}

// ---------------- K11: GSA attention (8 heads, hd=64), 4 waves x 16 tokens ----------------
__global__ __launch_bounds__(256) void k_gsa_attn(const float* __restrict__ Q3, const float* __restrict__ K3,
      const float* __restrict__ V3, float* __restrict__ AO2) {
  int h = blockIdx.x;
  __shared__ float qh[64][65], kh[64][65], vh[64][65];
  __shared__ float ps[4][64];
  for (int i = threadIdx.x; i < 4096; i += 256) {
    int t = i >> 6, d = i & 63;
    qh[t][d] = Q3[(size_t)t * 512 + h * 64 + d];
    kh[t][d] = K3[(size_t)t * 512 + h * 64 + d];
    vh[t][d] = V3[(size_t)t * 512 + h * 64 + d];
  }
  __syncthreads();
  int w = threadIdx.x >> 6, lane = threadIdx.x & 63;   // lane = s (then d)
  for (int tt = 0; tt < 16; tt++) {
    int t = w * 16 + tt;
    float acc = 0.f;
#pragma unroll 8
    for (int d = 0; d < 64; d++) acc = fmaf(qh[t][d], kh[lane][d], acc);
    acc *= 0.125f;                 // 1/sqrt(64)
    float m = acc;
#pragma unroll
    for (int o = 32; o > 0; o >>= 1) m = fmaxf(m, __shfl_xor(m, o, 64));
    float e = __expf(acc - m);
    float den = e;
#pragma unroll
    for (int o = 32; o > 0; o >>= 1) den += __shfl_xor(den, o, 64);
    ps[w][lane] = e / den;
    __syncthreads();
    float o2 = 0.f;
#pragma unroll 8
    for (int s = 0; s < 64; s++) o2 = fmaf(ps[w][s], vh[s][lane], o2);
    AO2[(size_t)t * 512 + h * 64 + lane] = o2;
    __syncthreads();
  }
}

// ---------------- K13: GSA LN2 + fc + swish (y = output tile of 256) ----------------
__global__ __launch_bounds__(256) void k_gsa_fc(const float* __restrict__ XB,
      const float* __restrict__ G, const float* __restrict__ Bta,
      const float* __restrict__ W, const float* __restrict__ B, float* __restrict__ H) {
  int t = blockIdx.x;
  int tid = threadIdx.x;
  __shared__ float xr[512];
  const float* x = XB + (size_t)t * 512;
  float v0 = x[tid], v1 = x[tid + 256];
  float sum = block_sum256(v0 + v1);
  float sq = block_sum256(v0 * v0 + v1 * v1);
  float m = sum * (1.f / 512.f);
  float rs = rsqrtf(sq * (1.f / 512.f) - m * m + EPSV);
  xr[tid] = (v0 - m) * rs * G[tid] + Bta[tid];
  xr[tid + 256] = (v1 - m) * rs * G[tid + 256] + Bta[tid + 256];
  __syncthreads();
  int o = blockIdx.y * 256 + tid;
  const float4* w = (const float4*)(W + (size_t)o * 512);
  float acc = 0.f;
#pragma unroll 8
  for (int c = 0; c < 128; c++) {
    float4 wv = w[c]; float4 xv = ((const float4*)xr)[c];
    acc = fmaf(wv.x, xv.x, acc); acc = fmaf(wv.y, xv.y, acc);
    acc = fmaf(wv.z, xv.z, acc); acc = fmaf(wv.w, xv.w, acc);
  }
  acc += B[o];
  H[(size_t)t * HIDE + o] = acc / (1.f + __expf(-1.702f * acc));
}

// ---------------- K14a: gated = x + h@proj.T + b (y = half) ----------------
__global__ __launch_bounds__(256) void k_gsa_gated(const float* __restrict__ XB, const float* __restrict__ HROW,
      const float* __restrict__ PW, const float* __restrict__ PB, float* __restrict__ GATED) {
  int t = blockIdx.x;
  int tid = threadIdx.x;
  __shared__ float hr[2048];
  const float4* hp = (const float4*)(HROW + (size_t)t * HIDE);
  for (int i = tid; i < 512; i += 256) ((float4*)hr)[i] = hp[i];
  __syncthreads();
  int o = blockIdx.y * 256 + tid;
  const float4* w = (const float4*)(PW + (size_t)o * HIDE);
  float acc = 0.f;
#pragma unroll 4
  for (int c = 0; c < 512; c++) {
    float4 wv = w[c]; float4 xv = ((const float4*)hr)[c];
    acc = fmaf(wv.x, xv.x, acc); acc = fmaf(wv.y, xv.y, acc);
    acc = fmaf(wv.z, xv.z, acc); acc = fmaf(wv.w, xv.w, acc);
  }
  GATED[(size_t)t * 512 + o] = acc + PB[o] + XB[(size_t)t * 512 + o];
}

// ---------------- K14b: hb = gated@butter.T + b ----------------
__global__ __launch_bounds__(256) void k_butter(const float* __restrict__ GATED,
      const float* __restrict__ BW, const float* __restrict__ BB, float* __restrict__ HB) {
  int t = blockIdx.x;
  int tid = threadIdx.x;
  __shared__ float gr[512];
  gr[tid] = GATED[(size_t)t * 512 + tid];
  gr[tid + 256] = GATED[(size_t)t * 512 + 256 + tid];
  __syncthreads();
  const float4* w = (const float4*)(BW + (size_t)tid * 512);
  float acc = 0.f;
#pragma unroll 8
  for (int c = 0; c < 128; c++) {
    float4 wv = w[c]; float4 xv = ((const float4*)gr)[c];
    acc = fmaf(wv.x, xv.x, acc); acc = fmaf(wv.y, xv.y, acc);
    acc = fmaf(wv.z, xv.z, acc); acc = fmaf(wv.w, xv.w, acc);
  }
  HB[(size_t)t * 256 + tid] = acc + BB[tid];
}

// ---------------- K15: classifier head + hazards + Y_hat + aux + feature2_pre ----------------
__global__ __launch_bounds__(256) void k_final(const float* __restrict__ HB,
      const float* __restrict__ CW, const float* __restrict__ CB,
      const float* __restrict__ ssum, const int* __restrict__ cnt,
      float* __restrict__ out) {
  int tid = threadIdx.x;
  float p0 = 0.f, p1 = 0.f;
  for (int i = tid; i < 16384; i += 256) {
    float h = HB[i];
    p0 = fmaf(h, CW[i], p0);
    p1 = fmaf(h, CW[16384 + i], p1);
  }
  p0 = block_sum256(p0);
  p1 = block_sum256(p1);
  if (tid == 0) {
    float l0 = p0 + CB[0], l1 = p1 + CB[1];
    out[0] = l0; out[1] = l1;
    out[2] = 1.f / (1.f + __expf(-l0));
    out[3] = 1.f / (1.f + __expf(-l1));
    out[4] = (l1 > l0) ? 1.f : 0.f;   // argmax, first max on ties
    float aux = 0.f;
    for (int i = 0; i < 16; i++) aux += (ssum[i] * (1.f / 64.f)) * ((float)cnt[i] * (1.f / 64.f));
    out[5] = aux * 4.f * 0.01f;       // * E * AUX_W
  }
  if (tid < 8) out[O_F2P + tid] = 0.f;
}

extern "C" void kernel_launch(void* const* d_in, const int* in_sizes, int n_in,
                              void* d_out, int out_size, void* d_ws, size_t ws_size,
                              hipStream_t stream) {
  const float* SF    = (const float*)d_in[0];
  const float* TOK   = (const float*)d_in[1];
  const float* LN1G  = (const float*)d_in[2];
  const float* LN1B  = (const float*)d_in[3];
  const float* LN2G  = (const float*)d_in[4];
  const float* LN2B  = (const float*)d_in[5];
  const float* QKVW  = (const float*)d_in[6];
  const float* QKVB  = (const float*)d_in[7];
  const float* OUTW  = (const float*)d_in[8];
  const float* OUTB  = (const float*)d_in[9];
  const float* MLPW  = (const float*)d_in[10];
  const float* MLPB  = (const float*)d_in[11];
  const float* GPW   = (const float*)d_in[12];
  const float* GSIM  = (const float*)d_in[13];
  const float* GTMP  = (const float*)d_in[14];
  const float* EW1   = (const float*)d_in[15];
  const float* EB1   = (const float*)d_in[16];
  const float* EW2   = (const float*)d_in[17];
  const float* EB2   = (const float*)d_in[18];
  const float* GL1G  = (const float*)d_in[19];
  const float* GL1B  = (const float*)d_in[20];
  const float* GQKVW = (const float*)d_in[21];
  const float* GQKVB = (const float*)d_in[22];
  const float* GOUTW = (const float*)d_in[23];
  const float* GOUTB = (const float*)d_in[24];
  const float* GL2G  = (const float*)d_in[25];
  const float* GL2B  = (const float*)d_in[26];
  const float* GFCW  = (const float*)d_in[27];
  const float* GFCB  = (const float*)d_in[28];
  const float* GPJW  = (const float*)d_in[29];
  const float* GPJB  = (const float*)d_in[30];
  const float* BTW   = (const float*)d_in[31];
  const float* BTB   = (const float*)d_in[32];
  const float* CLW   = (const float*)d_in[33];
  const float* CLB   = (const float*)d_in[34];

  float* ws  = (float*)d_ws;
  float* out = (float*)d_out;

  float* MU   = ws + OFF_MU;
  float* RSTD = ws + OFF_RSTD;
  float* KT   = ws + OFF_KT;
  float* VT   = ws + OFF_VT;
  float* KMAX = ws + OFF_KMAX;
  float* KMIN = ws + OFF_KMIN;
  float* Q    = ws + OFF_Q;
  float* AO   = ws + OFF_AO;
  float* AP   = ws + OFF_AP;
  float* QF   = ws + OFF_QF;
  float* GATE = ws + OFF_GATE;
  int*   EXPI = (int*)(ws + OFF_EXP);
  int*   POSI = (int*)(ws + OFF_POS);
  int*   KEEPI= (int*)(ws + OFF_KEEP);
  float* BUF  = ws + OFF_BUF;
  float* SSUM = ws + OFF_SSUM;
  int*   CNT  = (int*)(ws + OFF_CNT);
  float* HEXP = ws + OFF_HEXP;
  float* YEXP = ws + OFF_YEXP;
  float* CUR  = ws + OFF_CUR;
  float* Q3   = ws + OFF_Q3;
  float* K3   = ws + OFF_K3;
  float* V3   = ws + OFF_V3;
  float* AO2  = ws + OFF_AO2;
  float* XB   = ws + OFF_XB;
  float* HROW = ws + OFF_HROW;
  float* HBB  = ws + OFF_HB;
  float* GTD  = ws + OFF_GATED;

  k_zero<<<(ZERO_N + 255) / 256, 256, 0, stream>>>(BUF, ZERO_N);
  k_rowstats<<<LNUM * NSEQ, 64, 0, stream>>>(SF, MU, RSTD);
  k_kvgemm<<<dim3(8, 32, LNUM), 256, 0, stream>>>(SF, QKVW, QKVB, LN1G, LN1B, MU, RSTD, KT, VT);
  k_minmax<<<LNUM * 512, 256, 0, stream>>>(KT, KMAX, KMIN);
  k_q<<<dim3(TTOK, LNUM, 2), 256, 0, stream>>>(TOK, LN2G, LN2B, QKVW, QKVB, Q);
  k_attn<<<dim3(512, LNUM), 256, 0, stream>>>(KT, VT, Q, KMAX, KMIN, AO);
  k_rowgemm512<<<dim3(TTOK, LNUM, 2), 256, 0, stream>>>(AO, OUTW, OUTB, nullptr, AP, 512ull * 512ull, 512);
  k_rowgemm512<<<dim3(TTOK, LNUM, 2), 256, 0, stream>>>(AP, MLPW, MLPB, nullptr, QF, 512ull * 512ull, 512);
  k_gate<<<dim3(TTOK, LNUM), 256, 0, stream>>>(QF, GPW, GSIM, GTMP, GATE, EXPI, SSUM, CNT);
  k_route<<<LNUM, 64, 0, stream>>>(GATE, EXPI, POSI, KEEPI);
  k_scatter<<<dim3(TTOK, LNUM), 128, 0, stream>>>(QF, EXPI, POSI, KEEPI, BUF);
  k_moe_h<<<dim3(8, 16), 256, 0, stream>>>(BUF, EW1, EB1, HEXP);
  k_moe_y<<<dim3(8, 16), 256, 0, stream>>>(HEXP, EW2, EB2, YEXP);
  k_combine<<<TTOK, 512, 0, stream>>>(YEXP, EXPI, POSI, KEEPI, GATE, out + O_F1, out + O_F2, CUR);
  k_gsa_qkv<<<dim3(TTOK, 6), 256, 0, stream>>>(CUR, GL1G, GL1B, GQKVW, GQKVB, Q3, K3, V3);
  k_gsa_attn<<<8, 256, 0, stream>>>(Q3, K3, V3, AO2);
  k_rowgemm512<<<dim3(TTOK, 1, 2), 256, 0, stream>>>(AO2, GOUTW, GOUTB, CUR, XB, 0ull, 0);
  k_gsa_fc<<<dim3(TTOK, 8), 256, 0, stream>>>(XB, GL2G, GL2B, GFCW, GFCB, HROW);
  k_gsa_gated<<<dim3(TTOK, 2), 256, 0, stream>>>(XB, HROW, GPJW, GPJB, GTD);
  k_butter<<<TTOK, 256, 0, stream>>>(GTD, BTW, BTB, HBB);
  k_final<<<1, 256, 0, stream>>>(HBB, CLW, CLB, SSUM, CNT, out);
}

// Round 3
// 945.888 us; speedup vs baseline: 1.4210x; 1.1548x over previous
//
#include <hip/hip_runtime.h>
#include <math.h>

// LRENet_2: L=4, AD=D=512, T=64, N=4096, NC=2, PROJ=256, HID=2048, CAP=16
#define LNUM 4
#define ADIM 512
#define TTOK 64
#define NSEQ 4096
#define HIDE 2048
#define CAPE 16
#define EPSV 1e-5f

typedef __bf16 bf16;
typedef bf16 bf16x8 __attribute__((ext_vector_type(8)));
typedef float f32x4 __attribute__((ext_vector_type(4)));

// ---------------- workspace layout (float offsets) ----------------
#define OFF_KT      0
#define OFF_VT      (OFF_KT   + LNUM*512*NSEQ)
#define OFF_KMAX    (OFF_VT   + LNUM*512*NSEQ)
#define OFF_KMIN    (OFF_KMAX + LNUM*512)
#define OFF_Q       (OFF_KMIN + LNUM*512)
#define OFF_AO      (OFF_Q    + LNUM*TTOK*512)
#define OFF_AP      (OFF_AO   + LNUM*TTOK*512)
#define OFF_QF      (OFF_AP   + LNUM*TTOK*512)
#define OFF_GATE    (OFF_QF   + LNUM*TTOK*512)
#define OFF_EXP     (OFF_GATE + LNUM*TTOK)
#define OFF_POS     (OFF_EXP  + LNUM*TTOK)
#define OFF_KEEP    (OFF_POS  + LNUM*TTOK)
#define OFF_BUF     (OFF_KEEP + LNUM*TTOK)          // zeroed region starts here
#define OFF_SSUM    (OFF_BUF  + LNUM*4*CAPE*512)
#define OFF_CNT     (OFF_SSUM + LNUM*4)
#define ZERO_N      (LNUM*4*CAPE*512 + LNUM*4 + LNUM*4)
#define OFF_HEXP    (OFF_CNT  + LNUM*4)
#define OFF_YEXP    (OFF_HEXP + LNUM*4*CAPE*HIDE)
#define OFF_CUR     (OFF_YEXP + LNUM*4*CAPE*512)
#define OFF_Q3      (OFF_CUR  + TTOK*512)
#define OFF_K3      (OFF_Q3   + TTOK*512)
#define OFF_V3      (OFF_K3   + TTOK*512)
#define OFF_AO2     (OFF_V3   + TTOK*512)
#define OFF_XB      (OFF_AO2  + TTOK*512)
#define OFF_HROW    (OFF_XB   + TTOK*512)
#define OFF_HB      (OFF_HROW + TTOK*HIDE)
#define OFF_GATED   (OFF_HB   + TTOK*256)
// bf16 split arrays (counted in float slots = half the bf16 count)
#define OFF_AH      (OFF_GATED + TTOK*512)
#define OFF_AL      (OFF_AH + LNUM*NSEQ*256)
#define OFF_WH      (OFF_AL + LNUM*NSEQ*256)
#define OFF_WL      (OFF_WH + LNUM*1024*256)

// ---------------- output layout (floats) ----------------
#define O_F1   6
#define O_F2   (6 + LNUM*TTOK*512)
#define O_F2P  (O_F2 + LNUM*TTOK*512)

__device__ __forceinline__ float wave_sum(float v) {
#pragma unroll
  for (int o = 32; o > 0; o >>= 1) v += __shfl_down(v, o, 64);
  return v;
}

__device__ __forceinline__ float block_sum256(float v) {
  __shared__ float r[4];
  v = wave_sum(v);
  int wid = threadIdx.x >> 6, lane = threadIdx.x & 63;
  if (lane == 0) r[wid] = v;
  __syncthreads();
  float s = r[0] + r[1] + r[2] + r[3];
  __syncthreads();
  return s;
}

// ---------------- K0: zero scratch ----------------
__global__ void k_zero(float* __restrict__ p, int n) {
  int i = blockIdx.x * 256 + threadIdx.x;
  if (i < n) p[i] = 0.f;
}

// ---------------- K1: fused LN + split-bf16 convert of A panel ----------------
// one 64-thread block per (l, m) row: stats via wave reduce, then hi/lo bf16 write
__global__ __launch_bounds__(64) void k_cvt_a(const float* __restrict__ SF,
      const float* __restrict__ G, const float* __restrict__ Bta,
      bf16* __restrict__ AH, bf16* __restrict__ AL) {
  int row = blockIdx.x;            // l*4096 + m
  int l = row >> 12, m = row & 4095;
  int lane = threadIdx.x;
  const float* src = SF + (size_t)m * (LNUM * ADIM) + l * ADIM;
  float4 a = *(const float4*)(src + lane * 8);
  float4 b = *(const float4*)(src + lane * 8 + 4);
  float sum = (a.x + a.y) + (a.z + a.w) + (b.x + b.y) + (b.z + b.w);
  float sq = a.x*a.x + a.y*a.y + a.z*a.z + a.w*a.w + b.x*b.x + b.y*b.y + b.z*b.z + b.w*b.w;
  sum = wave_sum(sum); sq = wave_sum(sq);
  sum = __shfl(sum, 0, 64); sq = __shfl(sq, 0, 64);
  float mu = sum * (1.f / 512.f);
  float rs = rsqrtf(sq * (1.f / 512.f) - mu * mu + EPSV);
  float4 g0 = *(const float4*)(G + l * 512 + lane * 8);
  float4 g1 = *(const float4*)(G + l * 512 + lane * 8 + 4);
  float4 c0 = *(const float4*)(Bta + l * 512 + lane * 8);
  float4 c1 = *(const float4*)(Bta + l * 512 + lane * 8 + 4);
  float x[8];
  x[0] = (a.x - mu) * rs * g0.x + c0.x;  x[1] = (a.y - mu) * rs * g0.y + c0.y;
  x[2] = (a.z - mu) * rs * g0.z + c0.z;  x[3] = (a.w - mu) * rs * g0.w + c0.w;
  x[4] = (b.x - mu) * rs * g1.x + c1.x;  x[5] = (b.y - mu) * rs * g1.y + c1.y;
  x[6] = (b.z - mu) * rs * g1.z + c1.z;  x[7] = (b.w - mu) * rs * g1.w + c1.w;
  bf16x8 vh, vl;
#pragma unroll
  for (int j = 0; j < 8; j++) {
    bf16 h = (bf16)x[j];
    vh[j] = h;
    vl[j] = (bf16)(x[j] - (float)h);
  }
  *(bf16x8*)(AH + (size_t)row * 512 + lane * 8) = vh;
  *(bf16x8*)(AL + (size_t)row * 512 + lane * 8) = vl;
}

// ---------------- K1b: split-bf16 convert of W K/V rows ----------------
__global__ __launch_bounds__(64) void k_cvt_w(const float* __restrict__ Wqkv,
      bf16* __restrict__ WH, bf16* __restrict__ WL) {
  int row = blockIdx.x;            // l*1024 + r
  int l = row >> 10, r = row & 1023;
  int lane = threadIdx.x;
  const float* src = Wqkv + (size_t)l * 1536 * 512 + (size_t)(512 + r) * 512 + lane * 8;
  float4 a = *(const float4*)(src);
  float4 b = *(const float4*)(src + 4);
  float x[8] = {a.x, a.y, a.z, a.w, b.x, b.y, b.z, b.w};
  bf16x8 vh, vl;
#pragma unroll
  for (int j = 0; j < 8; j++) {
    bf16 h = (bf16)x[j];
    vh[j] = h;
    vl[j] = (bf16)(x[j] - (float)h);
  }
  *(bf16x8*)(WH + (size_t)row * 512 + lane * 8) = vh;
  *(bf16x8*)(WL + (size_t)row * 512 + lane * 8) = vl;
}

// ---------------- K2: split-bf16 MFMA GEMM -> K^T, V^T ----------------
// 128x128 tile, BK=32, 4 waves (2x2), each wave 4x4 MFMA 16x16x32 tiles, 3-term split
__global__ __launch_bounds__(256) void k_mfma_kv(
      const bf16* __restrict__ AH, const bf16* __restrict__ AL,
      const bf16* __restrict__ WH, const bf16* __restrict__ WL,
      const float* __restrict__ Bqkv,
      float* __restrict__ KT, float* __restrict__ VT) {
  __shared__ bf16 sAh[128*32], sAl[128*32], sWh[128*32], sWl[128*32];
  int l = blockIdx.z;
  int n0 = blockIdx.x * 128, m0 = blockIdx.y * 128;
  int tid = threadIdx.x;
  int lane = tid & 63;
  int w = tid >> 6;
  int wm = w >> 1, wn = w & 1;
  const bf16* gAh = AH + ((size_t)l * 4096 + m0) * 512;
  const bf16* gAl = AL + ((size_t)l * 4096 + m0) * 512;
  const bf16* gWh = WH + ((size_t)l * 1024 + n0) * 512;
  const bf16* gWl = WL + ((size_t)l * 1024 + n0) * 512;
  int ch0 = tid * 2, ch1 = tid * 2 + 1;
  int r0 = ch0 >> 2, q0 = (ch0 & 3) * 8;
  int r1 = ch1 >> 2, q1 = (ch1 & 3) * 8;
  int fr = lane & 15, fq = (lane >> 4) * 8;
  f32x4 acc[4][4] = {};
  for (int k0 = 0; k0 < 512; k0 += 32) {
    *(bf16x8*)&sAh[r0*32 + q0] = *(const bf16x8*)&gAh[(size_t)r0*512 + k0 + q0];
    *(bf16x8*)&sAh[r1*32 + q1] = *(const bf16x8*)&gAh[(size_t)r1*512 + k0 + q1];
    *(bf16x8*)&sAl[r0*32 + q0] = *(const bf16x8*)&gAl[(size_t)r0*512 + k0 + q0];
    *(bf16x8*)&sAl[r1*32 + q1] = *(const bf16x8*)&gAl[(size_t)r1*512 + k0 + q1];
    *(bf16x8*)&sWh[r0*32 + q0] = *(const bf16x8*)&gWh[(size_t)r0*512 + k0 + q0];
    *(bf16x8*)&sWh[r1*32 + q1] = *(const bf16x8*)&gWh[(size_t)r1*512 + k0 + q1];
    *(bf16x8*)&sWl[r0*32 + q0] = *(const bf16x8*)&gWl[(size_t)r0*512 + k0 + q0];
    *(bf16x8*)&sWl[r1*32 + q1] = *(const bf16x8*)&gWl[(size_t)r1*512 + k0 + q1];
    __syncthreads();
    bf16x8 ah[4], al[4], bh[4], bl[4];
#pragma unroll
    for (int i = 0; i < 4; i++) {
      ah[i] = *(const bf16x8*)&sAh[(wm*64 + i*16 + fr)*32 + fq];
      al[i] = *(const bf16x8*)&sAl[(wm*64 + i*16 + fr)*32 + fq];
      bh[i] = *(const bf16x8*)&sWh[(wn*64 + i*16 + fr)*32 + fq];
      bl[i] = *(const bf16x8*)&sWl[(wn*64 + i*16 + fr)*32 + fq];
    }
#pragma unroll
    for (int i = 0; i < 4; i++)
#pragma unroll
      for (int j = 0; j < 4; j++) {
        acc[i][j] = __builtin_amdgcn_mfma_f32_16x16x32_bf16(ah[i], bh[j], acc[i][j], 0, 0, 0);
        acc[i][j] = __builtin_amdgcn_mfma_f32_16x16x32_bf16(ah[i], bl[j], acc[i][j], 0, 0, 0);
        acc[i][j] = __builtin_amdgcn_mfma_f32_16x16x32_bf16(al[i], bh[j], acc[i][j], 0, 0, 0);
      }
    __syncthreads();
  }
  // epilogue: D row(m) = quad*4+reg, col(n) = lane&15
#pragma unroll
  for (int j = 0; j < 4; j++) {
    int n = n0 + wn*64 + j*16 + fr;
    float bias = Bqkv[l * 1536 + 512 + n];
    float* base = (n < 512) ? (KT + ((size_t)(l*512 + n)) * 4096)
                            : (VT + ((size_t)(l*512 + n - 512)) * 4096);
#pragma unroll
    for (int i = 0; i < 4; i++) {
      int mb = m0 + wm*64 + i*16 + (lane >> 4) * 4;
      float4 o = make_float4(acc[i][j][0] + bias, acc[i][j][1] + bias,
                             acc[i][j][2] + bias, acc[i][j][3] + bias);
      *(float4*)(base + mb) = o;
    }
  }
}

// ---------------- K3: per-head k min/max ----------------
__global__ __launch_bounds__(256) void k_minmax(const float* __restrict__ KT,
                                                float* __restrict__ kmax, float* __restrict__ kmin) {
  int row = blockIdx.x;            // l*512 + h
  const float4* k = (const float4*)(KT + (size_t)row * 4096);
  float mx = -3.4e38f, mn = 3.4e38f;
  for (int i = threadIdx.x; i < 1024; i += 256) {
    float4 v = k[i];
    mx = fmaxf(mx, fmaxf(fmaxf(v.x, v.y), fmaxf(v.z, v.w)));
    mn = fminf(mn, fminf(fminf(v.x, v.y), fminf(v.z, v.w)));
  }
#pragma unroll
  for (int o = 32; o > 0; o >>= 1) {
    mx = fmaxf(mx, __shfl_down(mx, o, 64));
    mn = fminf(mn, __shfl_down(mn, o, 64));
  }
  __shared__ float rmx[4], rmn[4];
  int wid = threadIdx.x >> 6, lane = threadIdx.x & 63;
  if (lane == 0) { rmx[wid] = mx; rmn[wid] = mn; }
  __syncthreads();
  if (threadIdx.x == 0) {
    kmax[row] = fmaxf(fmaxf(rmx[0], rmx[1]), fmaxf(rmx[2], rmx[3]));
    kmin[row] = fminf(fminf(rmn[0], rmn[1]), fminf(rmn[2], rmn[3]));
  }
}

// ---------------- K4: tok LN + Q projection (z-split halves) ----------------
__global__ __launch_bounds__(256) void k_q(const float* __restrict__ TOK,
      const float* __restrict__ G, const float* __restrict__ Bta,
      const float* __restrict__ Wqkv, const float* __restrict__ Bqkv,
      float* __restrict__ Q) {
  int t = blockIdx.x, l = blockIdx.y;
  int tid = threadIdx.x;
  __shared__ float xr[512];
  const float* x = TOK + ((size_t)l * TTOK + t) * ADIM;
  float v0 = x[tid], v1 = x[tid + 256];
  float sum = block_sum256(v0 + v1);
  float sq = block_sum256(v0 * v0 + v1 * v1);
  float m = sum * (1.f / 512.f);
  float rs = rsqrtf(sq * (1.f / 512.f) - m * m + EPSV);
  xr[tid]       = (v0 - m) * rs * G[l * 512 + tid] + Bta[l * 512 + tid];
  xr[tid + 256] = (v1 - m) * rs * G[l * 512 + tid + 256] + Bta[l * 512 + tid + 256];
  __syncthreads();
  int h = blockIdx.z * 256 + tid;
  const float4* w = (const float4*)(Wqkv + (size_t)l * 1536 * 512 + (size_t)h * 512);
  float acc = 0.f;
#pragma unroll 8
  for (int c = 0; c < 128; c++) {
    float4 wv = w[c]; float4 xv = ((const float4*)xr)[c];
    acc = fmaf(wv.x, xv.x, acc); acc = fmaf(wv.y, xv.y, acc);
    acc = fmaf(wv.z, xv.z, acc); acc = fmaf(wv.w, xv.w, acc);
  }
  Q[((size_t)l * TTOK + t) * 512 + h] = acc + Bqkv[l * 1536 + h];
}

// ---------------- K5: hd=1 attention, lanes-over-s, K/V in registers ----------------
__global__ __launch_bounds__(256) void k_attn(const float* __restrict__ KT, const float* __restrict__ VT,
      const float* __restrict__ Q, const float* __restrict__ kmax, const float* __restrict__ kmin,
      float* __restrict__ AO) {
  int h = blockIdx.x, l = blockIdx.y;
  int tid = threadIdx.x;
  int w = tid >> 6, lane = tid & 63;
  __shared__ float pden[4][64], pnum[4][64];
  size_t base = ((size_t)(l * 512 + h)) * 4096 + w * 1024;
  float kv[16], vv[16];
#pragma unroll
  for (int c = 0; c < 4; c++) {
    *(float4*)&kv[c*4] = *(const float4*)(KT + base + c * 256 + lane * 4);
    *(float4*)&vv[c*4] = *(const float4*)(VT + base + c * 256 + lane * 4);
  }
  float q_own = Q[((size_t)l * TTOK + lane) * 512 + h];
  float km = kmax[l * 512 + h], kn = kmin[l * 512 + h];
  for (int t = 0; t < 64; t++) {
    float qt = __shfl(q_own, t, 64);
    float mt = (qt >= 0.f) ? qt * km : qt * kn;   // exact softmax max (hd=1)
    float den = 0.f, num = 0.f;
#pragma unroll
    for (int i = 0; i < 16; i++) {
      float e = __expf(fmaf(qt, kv[i], -mt));
      den += e;
      num = fmaf(e, vv[i], num);
    }
#pragma unroll
    for (int o = 32; o > 0; o >>= 1) {
      den += __shfl_down(den, o, 64);
      num += __shfl_down(num, o, 64);
    }
    if (lane == 0) { pden[w][t] = den; pnum[w][t] = num; }
  }
  __syncthreads();
  if (w == 0) {
    float d = pden[0][lane] + pden[1][lane] + pden[2][lane] + pden[3][lane];
    float n = pnum[0][lane] + pnum[1][lane] + pnum[2][lane] + pnum[3][lane];
    AO[((size_t)l * TTOK + lane) * 512 + h] = n / d;
  }
}

// ---------------- K6: row GEMM (64-row in, 512 out, K=512), z-split, uniform s_loads ----------------
__global__ __launch_bounds__(256) void k_rowgemm512(const float* __restrict__ IN,
      const float* __restrict__ W, const float* __restrict__ B, const float* __restrict__ RES,
      float* __restrict__ OUT, unsigned long long wsl, int bsl) {
  int t = blockIdx.x, l = blockIdx.y;
  int row = l * gridDim.x + t;
  int tid = threadIdx.x;
  const float4* xr = (const float4*)(IN + (size_t)row * 512);   // wave-uniform -> s_load
  int h = blockIdx.z * 256 + tid;
  const float4* w = (const float4*)(W + (size_t)l * wsl + (size_t)h * 512);
  float acc = 0.f;
#pragma unroll 8
  for (int c = 0; c < 128; c++) {
    float4 wv = w[c]; float4 xv = xr[c];
    acc = fmaf(wv.x, xv.x, acc); acc = fmaf(wv.y, xv.y, acc);
    acc = fmaf(wv.z, xv.z, acc); acc = fmaf(wv.w, xv.w, acc);
  }
  float o = acc + B[l * bsl + h];
  if (RES) o += RES[(size_t)row * 512 + h];
  OUT[(size_t)row * 512 + h] = o;
}

// ---------------- K7a: MoE gating ----------------
__global__ __launch_bounds__(256) void k_gate(const float* __restrict__ QF,
      const float* __restrict__ PW, const float* __restrict__ SIM, const float* __restrict__ TEMP,
      float* __restrict__ gate, int* __restrict__ expert,
      float* __restrict__ ssum, int* __restrict__ cnt) {
  int t = blockIdx.x, l = blockIdx.y;
  int tid = threadIdx.x;
  __shared__ float sp[256];
  __shared__ float lg[4];
  const float* x = QF + ((size_t)l * TTOK + t) * 512;   // uniform -> s_load
  float p = 0.f;
  for (int c = 0; c < 512; c++) p = fmaf(x[c], PW[c * 256 + tid], p);
  float nrm = block_sum256(p * p);
  float pn = p / (sqrtf(nrm) + 1e-8f);
  sp[tid] = pn;
  __syncthreads();
  if (tid < 4) {
    float ls = 0.f, ns = 0.f;
    for (int j = 0; j < 256; j++) {
      float sv = SIM[j * 4 + tid];
      ls = fmaf(sp[j], sv, ls);
      ns = fmaf(sv, sv, ns);
    }
    float scale = __expf(fminf(TEMP[0], 4.6051701859880914f));  // min(temp, log 100)
    lg[tid] = ls / (sqrtf(ns) + 1e-8f) * scale;
  }
  __syncthreads();
  if (tid == 0) {
    float l0 = lg[0], l1 = lg[1], l2 = lg[2], l3 = lg[3];
    int best = 0; float bv = l0;
    if (l1 > bv) { best = 1; bv = l1; }
    if (l2 > bv) { best = 2; bv = l2; }
    if (l3 > bv) { best = 3; bv = l3; }
    float mx = fmaxf(fmaxf(l0, l1), fmaxf(l2, l3));
    float e0 = __expf(l0 - mx), e1 = __expf(l1 - mx), e2 = __expf(l2 - mx), e3 = __expf(l3 - mx);
    float inv = 1.f / (e0 + e1 + e2 + e3);
    float s0 = e0 * inv, s1 = e1 * inv, s2 = e2 * inv, s3 = e3 * inv;
    float sb = (best == 0) ? s0 : (best == 1) ? s1 : (best == 2) ? s2 : s3;
    gate[l * TTOK + t] = sb;
    expert[l * TTOK + t] = best;
    atomicAdd(&ssum[l * 4 + 0], s0); atomicAdd(&ssum[l * 4 + 1], s1);
    atomicAdd(&ssum[l * 4 + 2], s2); atomicAdd(&ssum[l * 4 + 3], s3);
    atomicAdd(&cnt[l * 4 + best], 1);
  }
}

// ---------------- K7b: capacity routing ----------------
__global__ __launch_bounds__(64) void k_route(const float* __restrict__ gate, const int* __restrict__ expert,
                                              int* __restrict__ pos, int* __restrict__ keep) {
  int l = blockIdx.x;
  int t = threadIdx.x;
  __shared__ float g[64];
  __shared__ int e[64];
  g[t] = gate[l * TTOK + t]; e[t] = expert[l * TTOK + t];
  __syncthreads();
  float gt = g[t]; int et = e[t];
  int p = 0;
  for (int u = 0; u < 64; u++)
    if (e[u] == et && (g[u] > gt || (g[u] == gt && u < t))) p++;
  pos[l * TTOK + t] = p;
  keep[l * TTOK + t] = (p < CAPE) ? 1 : 0;
}

// ---------------- K7c: scatter kept tokens into expert buffers ----------------
__global__ __launch_bounds__(128) void k_scatter(const float* __restrict__ QF, const int* __restrict__ expert,
      const int* __restrict__ pos, const int* __restrict__ keep, float* __restrict__ buf) {
  int t = blockIdx.x, l = blockIdx.y;
  int idx = l * TTOK + t;
  if (!keep[idx]) return;
  int e = expert[idx], p = pos[idx];
  const float4* src = (const float4*)(QF + ((size_t)l * TTOK + t) * 512);
  float4* dst = (float4*)(buf + (((size_t)(l * 4 + e)) * CAPE + p) * 512);
  dst[threadIdx.x] = src[threadIdx.x];
}

// ---------------- K8a: expert up-proj + exact gelu (acts via uniform s_loads) ----------------
__global__ __launch_bounds__(256) void k_moe_h(const float* __restrict__ buf, const float* __restrict__ W1,
      const float* __restrict__ B1, float* __restrict__ H) {
  int le = blockIdx.y;             // l*4 + e
  int e = le & 3;
  int col = blockIdx.x * 256 + threadIdx.x;
  const float* act = buf + (size_t)le * 16 * 512;          // wave-uniform
  const float* wp = W1 + (size_t)e * 512 * HIDE + col;
  float acc[16];
#pragma unroll
  for (int c = 0; c < 16; c++) acc[c] = 0.f;
  for (int k0 = 0; k0 < 512; k0 += 4) {
    float4 a[16];
#pragma unroll
    for (int c = 0; c < 16; c++) a[c] = *(const float4*)(act + c * 512 + k0);
#pragma unroll
    for (int j = 0; j < 4; j++) {
      float wv = wp[(size_t)(k0 + j) * HIDE];
#pragma unroll
      for (int c = 0; c < 16; c++) acc[c] = fmaf(((const float*)&a[c])[j], wv, acc[c]);
    }
  }
  float bias = B1[e * HIDE + col];
  float* outp = H + (size_t)le * 16 * HIDE + col;
#pragma unroll
  for (int c = 0; c < 16; c++) {
    float v = acc[c] + bias;
    outp[(size_t)c * HIDE] = 0.5f * v * (1.f + erff(v * 0.70710678118654752f));
  }
}

// ---------------- K8b: expert down-proj (k split across 4 waves, LDS reduce) ----------------
__global__ __launch_bounds__(256) void k_moe_y(const float* __restrict__ H, const float* __restrict__ W2,
      const float* __restrict__ B2, float* __restrict__ Y) {
  int le = blockIdx.y;
  int e = le & 3;
  int cl = threadIdx.x & 63, kq = threadIdx.x >> 6;
  int col = blockIdx.x * 64 + cl;
  const float* act = H + (size_t)le * 16 * HIDE + kq * 512;   // wave-uniform
  const float* wp = W2 + (size_t)e * HIDE * 512 + (size_t)(kq * 512) * 512 + col;
  float acc[16];
#pragma unroll
  for (int c = 0; c < 16; c++) acc[c] = 0.f;
  for (int k0 = 0; k0 < 512; k0 += 4) {
    float4 a[16];
#pragma unroll
    for (int c = 0; c < 16; c++) a[c] = *(const float4*)(act + c * HIDE + k0);
#pragma unroll
    for (int j = 0; j < 4; j++) {
      float wv = wp[(size_t)(k0 + j) * 512];
#pragma unroll
      for (int c = 0; c < 16; c++) acc[c] = fmaf(((const float*)&a[c])[j], wv, acc[c]);
    }
  }
  __shared__ float sacc[4][16][64];
#pragma unroll
  for (int c = 0; c < 16; c++) sacc[kq][c][cl] = acc[c];
  __syncthreads();
  if (kq == 0) {
    float bias = B2[e * 512 + col];
#pragma unroll
    for (int c = 0; c < 16; c++) {
      float tot = sacc[0][c][cl] + sacc[1][c][cl] + sacc[2][c][cl] + sacc[3][c][cl] + bias;
      Y[(size_t)le * 16 * 512 + (size_t)c * 512 + col] = tot;
    }
  }
}

// ---------------- K9: gather expert outputs, prefix over layers ----------------
__global__ __launch_bounds__(512) void k_combine(const float* __restrict__ Y, const int* __restrict__ expert,
      const int* __restrict__ pos, const int* __restrict__ keep, const float* __restrict__ gate,
      float* __restrict__ f1, float* __restrict__ f2, float* __restrict__ cur) {
  int t = blockIdx.x;
  int d = threadIdx.x;
  float acc = 0.f;
#pragma unroll
  for (int l = 0; l < LNUM; l++) {
    int idx = l * TTOK + t;
    float v = 0.f;
    if (keep[idx]) {
      int e = expert[idx], p = pos[idx];
      v = Y[(((size_t)(l * 4 + e)) * CAPE + p) * 512 + d] * gate[idx];
    }
    acc += v;
    f1[((size_t)l * TTOK + t) * 512 + d] = acc;
    f2[((size_t)l * TTOK + t) * 512 + d] = 0.f;
  }
  cur[(size_t)t * 512 + d] = acc * 0.25f;
}

// ---------------- K10: GSA LN1 + qkv (y = output tile of 256) ----------------
__global__ __launch_bounds__(256) void k_gsa_qkv(const float* __restrict__ CUR,
      const float* __restrict__ G, const float* __restrict__ Bta,
      const float* __restrict__ W, const float* __restrict__ B,
      float* __restrict__ Q3, float* __restrict__ K3, float* __restrict__ V3) {
  int t = blockIdx.x;
  int tid = threadIdx.x;
  __shared__ float xr[512];
  const float* x = CUR + (size_t)t * 512;
  float v0 = x[tid], v1 = x[tid + 256];
  float sum = block_sum256(v0 + v1);
  float sq = block_sum256(v0 * v0 + v1 * v1);
  float m = sum * (1.f / 512.f);
  float rs = rsqrtf(sq * (1.f / 512.f) - m * m + EPSV);
  xr[tid] = (v0 - m) * rs * G[tid] + Bta[tid];
  xr[tid + 256] = (v1 - m) * rs * G[tid + 256] + Bta[tid + 256];
  __syncthreads();
  int h = blockIdx.y * 256 + tid;
  const float4* w = (const float4*)(W + (size_t)h * 512);
  float acc = 0.f;
#pragma unroll 8
  for (int c = 0; c < 128; c++) {
    float4 wv = w[c]; float4 xv = ((const float4*)xr)[c];
    acc = fmaf(wv.x, xv.x, acc); acc = fmaf(wv.y, xv.y, acc);
    acc = fmaf(wv.z, xv.z, acc); acc = fmaf(wv.w, xv.w, acc);
  }
  float o = acc + B[h];
  if (h < 512) Q3[(size_t)t * 512 + h] = o;
  else if (h < 1024) K3[(size_t)t * 512 + (h - 512)] = o;
  else V3[(size_t)t * 512 + (h - 1024)] = o;
}

// ---------------- K11: GSA attention (8 heads, hd=64), 4 waves x 16 tokens ----------------
__global__ __launch_bounds__(256) void k_gsa_attn(const float* __restrict__ Q3, const float* __restrict__ K3,
      const float* __restrict__ V3, float* __restrict__ AO2) {
  int h = blockIdx.x;
  __shared__ float qh[64][65], kh[64][65], vh[64][65];
  __shared__ float ps[4][64];
  for (int i = threadIdx.x; i < 4096; i += 256) {
    int t = i >> 6, d = i & 63;
    qh[t][d] = Q3[(size_t)t * 512 + h * 64 + d];
    kh[t][d] = K3[(size_t)t * 512 + h * 64 + d];
    vh[t][d] = V3[(size_t)t * 512 + h * 64 + d];
  }
  __syncthreads();
  int w = threadIdx.x >> 6, lane = threadIdx.x & 63;   // lane = s (then d)
  for (int tt = 0; tt < 16; tt++) {
    int t = w * 16 + tt;
    float acc = 0.f;
#pragma unroll 8
    for (int d = 0; d < 64; d++) acc = fmaf(qh[t][d], kh[lane][d], acc);
    acc *= 0.125f;                 // 1/sqrt(64)
    float m = acc;
#pragma unroll
    for (int o = 32; o > 0; o >>= 1) m = fmaxf(m, __shfl_xor(m, o, 64));
    float e = __expf(acc - m);
    float den = e;
#pragma unroll
    for (int o = 32; o > 0; o >>= 1) den += __shfl_xor(den, o, 64);
    ps[w][lane] = e / den;
    __syncthreads();
    float o2 = 0.f;
#pragma unroll 8
    for (int s = 0; s < 64; s++) o2 = fmaf(ps[w][s], vh[s][lane], o2);
    AO2[(size_t)t * 512 + h * 64 + lane] = o2;
    __syncthreads();
  }
}

// ---------------- K13: GSA LN2 + fc + swish (y = output tile of 256) ----------------
__global__ __launch_bounds__(256) void k_gsa_fc(const float* __restrict__ XB,
      const float* __restrict__ G, const float* __restrict__ Bta,
      const float* __restrict__ W, const float* __restrict__ B, float* __restrict__ H) {
  int t = blockIdx.x;
  int tid = threadIdx.x;
  __shared__ float xr[512];
  const float* x = XB + (size_t)t * 512;
  float v0 = x[tid], v1 = x[tid + 256];
  float sum = block_sum256(v0 + v1);
  float sq = block_sum256(v0 * v0 + v1 * v1);
  float m = sum * (1.f / 512.f);
  float rs = rsqrtf(sq * (1.f / 512.f) - m * m + EPSV);
  xr[tid] = (v0 - m) * rs * G[tid] + Bta[tid];
  xr[tid + 256] = (v1 - m) * rs * G[tid + 256] + Bta[tid + 256];
  __syncthreads();
  int o = blockIdx.y * 256 + tid;
  const float4* w = (const float4*)(W + (size_t)o * 512);
  float acc = 0.f;
#pragma unroll 8
  for (int c = 0; c < 128; c++) {
    float4 wv = w[c]; float4 xv = ((const float4*)xr)[c];
    acc = fmaf(wv.x, xv.x, acc); acc = fmaf(wv.y, xv.y, acc);
    acc = fmaf(wv.z, xv.z, acc); acc = fmaf(wv.w, xv.w, acc);
  }
  acc += B[o];
  H[(size_t)t * HIDE + o] = acc / (1.f + __expf(-1.702f * acc));
}

// ---------------- K14a: gated = x + h@proj.T + b (uniform s_loads) ----------------
__global__ __launch_bounds__(256) void k_gsa_gated(const float* __restrict__ XB, const float* __restrict__ HROW,
      const float* __restrict__ PW, const float* __restrict__ PB, float* __restrict__ GATED) {
  int t = blockIdx.x;
  int tid = threadIdx.x;
  const float4* hp = (const float4*)(HROW + (size_t)t * HIDE);  // wave-uniform
  int o = blockIdx.y * 256 + tid;
  const float4* w = (const float4*)(PW + (size_t)o * HIDE);
  float acc = 0.f;
#pragma unroll 4
  for (int c = 0; c < 512; c++) {
    float4 wv = w[c]; float4 xv = hp[c];
    acc = fmaf(wv.x, xv.x, acc); acc = fmaf(wv.y, xv.y, acc);
    acc = fmaf(wv.z, xv.z, acc); acc = fmaf(wv.w, xv.w, acc);
  }
  GATED[(size_t)t * 512 + o] = acc + PB[o] + XB[(size_t)t * 512 + o];
}

// ---------------- K14b: hb = gated@butter.T + b ----------------
__global__ __launch_bounds__(256) void k_butter(const float* __restrict__ GATED,
      const float* __restrict__ BW, const float* __restrict__ BB, float* __restrict__ HB) {
  int t = blockIdx.x;
  int tid = threadIdx.x;
  const float4* gr = (const float4*)(GATED + (size_t)t * 512);  // wave-uniform
  const float4* w = (const float4*)(BW + (size_t)tid * 512);
  float acc = 0.f;
#pragma unroll 8
  for (int c = 0; c < 128; c++) {
    float4 wv = w[c]; float4 xv = gr[c];
    acc = fmaf(wv.x, xv.x, acc); acc = fmaf(wv.y, xv.y, acc);
    acc = fmaf(wv.z, xv.z, acc); acc = fmaf(wv.w, xv.w, acc);
  }
  HB[(size_t)t * 256 + tid] = acc + BB[tid];
}

// ---------------- K15: classifier head + hazards + Y_hat + aux + feature2_pre ----------------
__global__ __launch_bounds__(256) void k_final(const float* __restrict__ HB,
      const float* __restrict__ CW, const float* __restrict__ CB,
      const float* __restrict__ ssum, const int* __restrict__ cnt,
      float* __restrict__ out) {
  int tid = threadIdx.x;
  float p0 = 0.f, p1 = 0.f;
  for (int i = tid; i < 16384; i += 256) {
    float h = HB[i];
    p0 = fmaf(h, CW[i], p0);
    p1 = fmaf(h, CW[16384 + i], p1);
  }
  p0 = block_sum256(p0);
  p1 = block_sum256(p1);
  if (tid == 0) {
    float l0 = p0 + CB[0], l1 = p1 + CB[1];
    out[0] = l0; out[1] = l1;
    out[2] = 1.f / (1.f + __expf(-l0));
    out[3] = 1.f / (1.f + __expf(-l1));
    out[4] = (l1 > l0) ? 1.f : 0.f;   // argmax, first max on ties
    float aux = 0.f;
    for (int i = 0; i < 16; i++) aux += (ssum[i] * (1.f / 64.f)) * ((float)cnt[i] * (1.f / 64.f));
    out[5] = aux * 4.f * 0.01f;       // * E * AUX_W
  }
  if (tid < 8) out[O_F2P + tid] = 0.f;
}

extern "C" void kernel_launch(void* const* d_in, const int* in_sizes, int n_in,
                              void* d_out, int out_size, void* d_ws, size_t ws_size,
                              hipStream_t stream) {
  const float* SF    = (const float*)d_in[0];
  const float* TOK   = (const float*)d_in[1];
  const float* LN1G  = (const float*)d_in[2];
  const float* LN1B  = (const float*)d_in[3];
  const float* LN2G  = (const float*)d_in[4];
  const float* LN2B  = (const float*)d_in[5];
  const float* QKVW  = (const float*)d_in[6];
  const float* QKVB  = (const float*)d_in[7];
  const float* OUTW  = (const float*)d_in[8];
  const float* OUTB  = (const float*)d_in[9];
  const float* MLPW  = (const float*)d_in[10];
  const float* MLPB  = (const float*)d_in[11];
  const float* GPW   = (const float*)d_in[12];
  const float* GSIM  = (const float*)d_in[13];
  const float* GTMP  = (const float*)d_in[14];
  const float* EW1   = (const float*)d_in[15];
  const float* EB1   = (const float*)d_in[16];
  const float* EW2   = (const float*)d_in[17];
  const float* EB2   = (const float*)d_in[18];
  const float* GL1G  = (const float*)d_in[19];
  const float* GL1B  = (const float*)d_in[20];
  const float* GQKVW = (const float*)d_in[21];
  const float* GQKVB = (const float*)d_in[22];
  const float* GOUTW = (const float*)d_in[23];
  const float* GOUTB = (const float*)d_in[24];
  const float* GL2G  = (const float*)d_in[25];
  const float* GL2B  = (const float*)d_in[26];
  const float* GFCW  = (const float*)d_in[27];
  const float* GFCB  = (const float*)d_in[28];
  const float* GPJW  = (const float*)d_in[29];
  const float* GPJB  = (const float*)d_in[30];
  const float* BTW   = (const float*)d_in[31];
  const float* BTB   = (const float*)d_in[32];
  const float* CLW   = (const float*)d_in[33];
  const float* CLB   = (const float*)d_in[34];

  float* ws  = (float*)d_ws;
  float* out = (float*)d_out;

  float* KT   = ws + OFF_KT;
  float* VT   = ws + OFF_VT;
  float* KMAX = ws + OFF_KMAX;
  float* KMIN = ws + OFF_KMIN;
  float* Q    = ws + OFF_Q;
  float* AO   = ws + OFF_AO;
  float* AP   = ws + OFF_AP;
  float* QF   = ws + OFF_QF;
  float* GATE = ws + OFF_GATE;
  int*   EXPI = (int*)(ws + OFF_EXP);
  int*   POSI = (int*)(ws + OFF_POS);
  int*   KEEPI= (int*)(ws + OFF_KEEP);
  float* BUF  = ws + OFF_BUF;
  float* SSUM = ws + OFF_SSUM;
  int*   CNT  = (int*)(ws + OFF_CNT);
  float* HEXP = ws + OFF_HEXP;
  float* YEXP = ws + OFF_YEXP;
  float* CUR  = ws + OFF_CUR;
  float* Q3   = ws + OFF_Q3;
  float* K3   = ws + OFF_K3;
  float* V3   = ws + OFF_V3;
  float* AO2  = ws + OFF_AO2;
  float* XB   = ws + OFF_XB;
  float* HROW = ws + OFF_HROW;
  float* HBB  = ws + OFF_HB;
  float* GTD  = ws + OFF_GATED;
  bf16*  AH   = (bf16*)(ws + OFF_AH);
  bf16*  AL   = (bf16*)(ws + OFF_AL);
  bf16*  WH   = (bf16*)(ws + OFF_WH);
  bf16*  WL   = (bf16*)(ws + OFF_WL);

  k_zero<<<(ZERO_N + 255) / 256, 256, 0, stream>>>(BUF, ZERO_N);
  k_cvt_a<<<LNUM * NSEQ, 64, 0, stream>>>(SF, LN1G, LN1B, AH, AL);
  k_cvt_w<<<LNUM * 1024, 64, 0, stream>>>(QKVW, WH, WL);
  k_mfma_kv<<<dim3(8, 32, LNUM), 256, 0, stream>>>(AH, AL, WH, WL, QKVB, KT, VT);
  k_minmax<<<LNUM * 512, 256, 0, stream>>>(KT, KMAX, KMIN);
  k_q<<<dim3(TTOK, LNUM, 2), 256, 0, stream>>>(TOK, LN2G, LN2B, QKVW, QKVB, Q);
  k_attn<<<dim3(512, LNUM), 256, 0, stream>>>(KT, VT, Q, KMAX, KMIN, AO);
  k_rowgemm512<<<dim3(TTOK, LNUM, 2), 256, 0, stream>>>(AO, OUTW, OUTB, nullptr, AP, 512ull * 512ull, 512);
  k_rowgemm512<<<dim3(TTOK, LNUM, 2), 256, 0, stream>>>(AP, MLPW, MLPB, nullptr, QF, 512ull * 512ull, 512);
  k_gate<<<dim3(TTOK, LNUM), 256, 0, stream>>>(QF, GPW, GSIM, GTMP, GATE, EXPI, SSUM, CNT);
  k_route<<<LNUM, 64, 0, stream>>>(GATE, EXPI, POSI, KEEPI);
  k_scatter<<<dim3(TTOK, LNUM), 128, 0, stream>>>(QF, EXPI, POSI, KEEPI, BUF);
  k_moe_h<<<dim3(8, 16), 256, 0, stream>>>(BUF, EW1, EB1, HEXP);
  k_moe_y<<<dim3(8, 16), 256, 0, stream>>>(HEXP, EW2, EB2, YEXP);
  k_combine<<<TTOK, 512, 0, stream>>>(YEXP, EXPI, POSI, KEEPI, GATE, out + O_F1, out + O_F2, CUR);
  k_gsa_qkv<<<dim3(TTOK, 6), 256, 0, stream>>>(CUR, GL1G, GL1B, GQKVW, GQKVB, Q3, K3, V3);
  k_gsa_attn<<<8, 256, 0, stream>>>(Q3, K3, V3, AO2);
  k_rowgemm512<<<dim3(TTOK, 1, 2), 256, 0, stream>>>(AO2, GOUTW, GOUTB, CUR, XB, 0ull, 0);
  k_gsa_fc<<<dim3(TTOK, 8), 256, 0, stream>>>(XB, GL2G, GL2B, GFCW, GFCB, HROW);
  k_gsa_gated<<<dim3(TTOK, 2), 256, 0, stream>>>(XB, HROW, GPJW, GPJB, GTD);
  k_butter<<<TTOK, 256, 0, stream>>>(GTD, BTW, BTB, HBB);
  k_final<<<1, 256, 0, stream>>>(HBB, CLW, CLB, SSUM, CNT, out);
}

// Round 4
// 818.284 us; speedup vs baseline: 1.6426x; 1.1559x over previous
//
#include <hip/hip_runtime.h>
#include <math.h>

// LRENet_2: L=4, AD=D=512, T=64, N=4096, NC=2, PROJ=256, HID=2048, CAP=16
#define LNUM 4
#define ADIM 512
#define TTOK 64
#define NSEQ 4096
#define HIDE 2048
#define CAPE 16
#define EPSV 1e-5f

typedef __bf16 bf16;
typedef bf16 bf16x8 __attribute__((ext_vector_type(8)));
typedef float f32x4 __attribute__((ext_vector_type(4)));

// ---------------- workspace layout (float offsets) ----------------
// zero region (atomic-GEMM outputs + MoE buf) first, zeroed every launch
#define OFF_BUF   0
#define OFF_SSUM  (OFF_BUF  + 131072)
#define OFF_CNT   (OFF_SSUM + 16)
#define OFF_Q     (OFF_CNT  + 16)
#define OFF_AP    (OFF_Q    + 131072)
#define OFF_QF    (OFF_AP   + 131072)
#define OFF_P     (OFF_QF   + 131072)
#define OFF_QKV3  (OFF_P    + 65536)
#define OFF_XB    (OFF_QKV3 + 98304)
#define OFF_HROW  (OFF_XB   + 32768)
#define OFF_GTD   (OFF_HROW + 131072)
#define OFF_HB    (OFF_GTD  + 32768)
#define ZERO_N    (OFF_HB   + 16384)
// non-zeroed
#define OFF_KT    ZERO_N
#define OFF_VT    (OFF_KT   + LNUM*512*NSEQ)
#define OFF_KMAX  (OFF_VT   + LNUM*512*NSEQ)
#define OFF_KMIN  (OFF_KMAX + LNUM*512)
#define OFF_AO    (OFF_KMIN + LNUM*512)   // shared: TN -> AO -> XN2 -> XN3 (sequential lifetimes)
#define OFF_GATE  (OFF_AO   + 131072)
#define OFF_EXP   (OFF_GATE + 256)
#define OFF_POS   (OFF_EXP  + 256)
#define OFF_KEEP  (OFF_POS  + 256)
#define OFF_HEXP  (OFF_KEEP + 256)
#define OFF_CUR   (OFF_HEXP + LNUM*4*CAPE*HIDE)
#define OFF_AO2   (OFF_CUR  + TTOK*512)
#define OFF_AH    (OFF_AO2  + TTOK*512)   // bf16 (float slots = half count); YEXP aliases (AH dead post-mfma)
#define OFF_AL    (OFF_AH + LNUM*NSEQ*256)
#define OFF_WH    (OFF_AL + LNUM*NSEQ*256)
#define OFF_WL    (OFF_WH + LNUM*1024*256)
#define OFF_YEXP  OFF_AH

// ---------------- output layout (floats) ----------------
#define O_F1   6
#define O_F2   (6 + LNUM*TTOK*512)
#define O_F2P  (O_F2 + LNUM*TTOK*512)

__device__ __forceinline__ float wave_sum(float v) {
#pragma unroll
  for (int o = 32; o > 0; o >>= 1) v += __shfl_down(v, o, 64);
  return v;
}
__device__ __forceinline__ float wave_sum_all(float v) {
#pragma unroll
  for (int o = 32; o > 0; o >>= 1) v += __shfl_xor(v, o, 64);
  return v;
}
__device__ __forceinline__ float block_sum256(float v) {
  __shared__ float r[4];
  v = wave_sum(v);
  int wid = threadIdx.x >> 6, lane = threadIdx.x & 63;
  if (lane == 0) r[wid] = v;
  __syncthreads();
  float s = r[0] + r[1] + r[2] + r[3];
  __syncthreads();
  return s;
}

// ---------------- zero scratch ----------------
__global__ void k_zero(float* __restrict__ p, int n) {
  int i = blockIdx.x * 256 + threadIdx.x;
  if (i < n) p[i] = 0.f;
}

// ---------------- LN + split-bf16 convert of A panel ----------------
__global__ __launch_bounds__(64) void k_cvt_a(const float* __restrict__ SF,
      const float* __restrict__ G, const float* __restrict__ Bta,
      bf16* __restrict__ AH, bf16* __restrict__ AL) {
  int row = blockIdx.x;            // l*4096 + m
  int l = row >> 12, m = row & 4095;
  int lane = threadIdx.x;
  const float* src = SF + (size_t)m * (LNUM * ADIM) + l * ADIM;
  float4 a = *(const float4*)(src + lane * 8);
  float4 b = *(const float4*)(src + lane * 8 + 4);
  float sum = (a.x + a.y) + (a.z + a.w) + (b.x + b.y) + (b.z + b.w);
  float sq = a.x*a.x + a.y*a.y + a.z*a.z + a.w*a.w + b.x*b.x + b.y*b.y + b.z*b.z + b.w*b.w;
  sum = wave_sum_all(sum); sq = wave_sum_all(sq);
  float mu = sum * (1.f / 512.f);
  float rs = rsqrtf(sq * (1.f / 512.f) - mu * mu + EPSV);
  float4 g0 = *(const float4*)(G + l * 512 + lane * 8);
  float4 g1 = *(const float4*)(G + l * 512 + lane * 8 + 4);
  float4 c0 = *(const float4*)(Bta + l * 512 + lane * 8);
  float4 c1 = *(const float4*)(Bta + l * 512 + lane * 8 + 4);
  float x[8];
  x[0] = (a.x - mu) * rs * g0.x + c0.x;  x[1] = (a.y - mu) * rs * g0.y + c0.y;
  x[2] = (a.z - mu) * rs * g0.z + c0.z;  x[3] = (a.w - mu) * rs * g0.w + c0.w;
  x[4] = (b.x - mu) * rs * g1.x + c1.x;  x[5] = (b.y - mu) * rs * g1.y + c1.y;
  x[6] = (b.z - mu) * rs * g1.z + c1.z;  x[7] = (b.w - mu) * rs * g1.w + c1.w;
  bf16x8 vh, vl;
#pragma unroll
  for (int j = 0; j < 8; j++) {
    bf16 h = (bf16)x[j];
    vh[j] = h;
    vl[j] = (bf16)(x[j] - (float)h);
  }
  *(bf16x8*)(AH + (size_t)row * 512 + lane * 8) = vh;
  *(bf16x8*)(AL + (size_t)row * 512 + lane * 8) = vl;
}

// ---------------- split-bf16 convert of W K/V rows ----------------
__global__ __launch_bounds__(64) void k_cvt_w(const float* __restrict__ Wqkv,
      bf16* __restrict__ WH, bf16* __restrict__ WL) {
  int row = blockIdx.x;            // l*1024 + r
  int l = row >> 10, r = row & 1023;
  int lane = threadIdx.x;
  const float* src = Wqkv + (size_t)l * 1536 * 512 + (size_t)(512 + r) * 512 + lane * 8;
  float4 a = *(const float4*)(src);
  float4 b = *(const float4*)(src + 4);
  float x[8] = {a.x, a.y, a.z, a.w, b.x, b.y, b.z, b.w};
  bf16x8 vh, vl;
#pragma unroll
  for (int j = 0; j < 8; j++) {
    bf16 h = (bf16)x[j];
    vh[j] = h;
    vl[j] = (bf16)(x[j] - (float)h);
  }
  *(bf16x8*)(WH + (size_t)row * 512 + lane * 8) = vh;
  *(bf16x8*)(WL + (size_t)row * 512 + lane * 8) = vl;
}

// ---------------- split-bf16 MFMA GEMM -> K^T, V^T ----------------
__global__ __launch_bounds__(256) void k_mfma_kv(
      const bf16* __restrict__ AH, const bf16* __restrict__ AL,
      const bf16* __restrict__ WH, const bf16* __restrict__ WL,
      const float* __restrict__ Bqkv,
      float* __restrict__ KT, float* __restrict__ VT) {
  __shared__ bf16 sAh[128*32], sAl[128*32], sWh[128*32], sWl[128*32];
  int l = blockIdx.z;
  int n0 = blockIdx.x * 128, m0 = blockIdx.y * 128;
  int tid = threadIdx.x;
  int lane = tid & 63;
  int w = tid >> 6;
  int wm = w >> 1, wn = w & 1;
  const bf16* gAh = AH + ((size_t)l * 4096 + m0) * 512;
  const bf16* gAl = AL + ((size_t)l * 4096 + m0) * 512;
  const bf16* gWh = WH + ((size_t)l * 1024 + n0) * 512;
  const bf16* gWl = WL + ((size_t)l * 1024 + n0) * 512;
  int ch0 = tid * 2, ch1 = tid * 2 + 1;
  int r0 = ch0 >> 2, q0 = (ch0 & 3) * 8;
  int r1 = ch1 >> 2, q1 = (ch1 & 3) * 8;
  int fr = lane & 15, fq = (lane >> 4) * 8;
  f32x4 acc[4][4] = {};
  for (int k0 = 0; k0 < 512; k0 += 32) {
    *(bf16x8*)&sAh[r0*32 + q0] = *(const bf16x8*)&gAh[(size_t)r0*512 + k0 + q0];
    *(bf16x8*)&sAh[r1*32 + q1] = *(const bf16x8*)&gAh[(size_t)r1*512 + k0 + q1];
    *(bf16x8*)&sAl[r0*32 + q0] = *(const bf16x8*)&gAl[(size_t)r0*512 + k0 + q0];
    *(bf16x8*)&sAl[r1*32 + q1] = *(const bf16x8*)&gAl[(size_t)r1*512 + k0 + q1];
    *(bf16x8*)&sWh[r0*32 + q0] = *(const bf16x8*)&gWh[(size_t)r0*512 + k0 + q0];
    *(bf16x8*)&sWh[r1*32 + q1] = *(const bf16x8*)&gWh[(size_t)r1*512 + k0 + q1];
    *(bf16x8*)&sWl[r0*32 + q0] = *(const bf16x8*)&gWl[(size_t)r0*512 + k0 + q0];
    *(bf16x8*)&sWl[r1*32 + q1] = *(const bf16x8*)&gWl[(size_t)r1*512 + k0 + q1];
    __syncthreads();
    bf16x8 ah[4], al[4], bh[4], bl[4];
#pragma unroll
    for (int i = 0; i < 4; i++) {
      ah[i] = *(const bf16x8*)&sAh[(wm*64 + i*16 + fr)*32 + fq];
      al[i] = *(const bf16x8*)&sAl[(wm*64 + i*16 + fr)*32 + fq];
      bh[i] = *(const bf16x8*)&sWh[(wn*64 + i*16 + fr)*32 + fq];
      bl[i] = *(const bf16x8*)&sWl[(wn*64 + i*16 + fr)*32 + fq];
    }
#pragma unroll
    for (int i = 0; i < 4; i++)
#pragma unroll
      for (int j = 0; j < 4; j++) {
        acc[i][j] = __builtin_amdgcn_mfma_f32_16x16x32_bf16(ah[i], bh[j], acc[i][j], 0, 0, 0);
        acc[i][j] = __builtin_amdgcn_mfma_f32_16x16x32_bf16(ah[i], bl[j], acc[i][j], 0, 0, 0);
        acc[i][j] = __builtin_amdgcn_mfma_f32_16x16x32_bf16(al[i], bh[j], acc[i][j], 0, 0, 0);
      }
    __syncthreads();
  }
#pragma unroll
  for (int j = 0; j < 4; j++) {
    int n = n0 + wn*64 + j*16 + fr;
    float bias = Bqkv[l * 1536 + 512 + n];
    float* base = (n < 512) ? (KT + ((size_t)(l*512 + n)) * 4096)
                            : (VT + ((size_t)(l*512 + n - 512)) * 4096);
#pragma unroll
    for (int i = 0; i < 4; i++) {
      int mb = m0 + wm*64 + i*16 + (lane >> 4) * 4;
      float4 o = make_float4(acc[i][j][0] + bias, acc[i][j][1] + bias,
                             acc[i][j][2] + bias, acc[i][j][3] + bias);
      *(float4*)(base + mb) = o;
    }
  }
}

// ---------------- per-head k min/max ----------------
__global__ __launch_bounds__(256) void k_minmax(const float* __restrict__ KT,
                                                float* __restrict__ kmax, float* __restrict__ kmin) {
  int row = blockIdx.x;            // l*512 + h
  const float4* k = (const float4*)(KT + (size_t)row * 4096);
  float mx = -3.4e38f, mn = 3.4e38f;
  for (int i = threadIdx.x; i < 1024; i += 256) {
    float4 v = k[i];
    mx = fmaxf(mx, fmaxf(fmaxf(v.x, v.y), fmaxf(v.z, v.w)));
    mn = fminf(mn, fminf(fminf(v.x, v.y), fminf(v.z, v.w)));
  }
#pragma unroll
  for (int o = 32; o > 0; o >>= 1) {
    mx = fmaxf(mx, __shfl_down(mx, o, 64));
    mn = fminf(mn, __shfl_down(mn, o, 64));
  }
  __shared__ float rmx[4], rmn[4];
  int wid = threadIdx.x >> 6, lane = threadIdx.x & 63;
  if (lane == 0) { rmx[wid] = mx; rmn[wid] = mn; }
  __syncthreads();
  if (threadIdx.x == 0) {
    kmax[row] = fmaxf(fmaxf(rmx[0], rmx[1]), fmaxf(rmx[2], rmx[3]));
    kmin[row] = fminf(fminf(rmn[0], rmn[1]), fminf(rmn[2], rmn[3]));
  }
}

// ---------------- generic row LayerNorm (64 rows per l) ----------------
__global__ __launch_bounds__(64) void k_ln(const float* __restrict__ IN,
      const float* __restrict__ G, const float* __restrict__ B,
      float* __restrict__ OUT, int gstride) {
  int t = blockIdx.x, l = blockIdx.y;
  int row = l * 64 + t;
  int lane = threadIdx.x;
  const float* x = IN + (size_t)row * 512 + lane * 8;
  float4 a = ((const float4*)x)[0], b = ((const float4*)x)[1];
  float sum = (a.x + a.y) + (a.z + a.w) + (b.x + b.y) + (b.z + b.w);
  float sq = a.x*a.x + a.y*a.y + a.z*a.z + a.w*a.w + b.x*b.x + b.y*b.y + b.z*b.z + b.w*b.w;
  sum = wave_sum_all(sum); sq = wave_sum_all(sq);
  float mu = sum * (1.f / 512.f);
  float rs = rsqrtf(sq * (1.f / 512.f) - mu * mu + EPSV);
  const float* gp = G + l * gstride + lane * 8;
  const float* bp = B + l * gstride + lane * 8;
  float4 g0 = ((const float4*)gp)[0], g1 = ((const float4*)gp)[1];
  float4 c0 = ((const float4*)bp)[0], c1 = ((const float4*)bp)[1];
  float4 o0, o1;
  o0.x = (a.x - mu) * rs * g0.x + c0.x;  o0.y = (a.y - mu) * rs * g0.y + c0.y;
  o0.z = (a.z - mu) * rs * g0.z + c0.z;  o0.w = (a.w - mu) * rs * g0.w + c0.w;
  o1.x = (b.x - mu) * rs * g1.x + c1.x;  o1.y = (b.y - mu) * rs * g1.y + c1.y;
  o1.z = (b.z - mu) * rs * g1.z + c1.z;  o1.w = (b.w - mu) * rs * g1.w + c1.w;
  float* op = OUT + (size_t)row * 512 + lane * 8;
  ((float4*)op)[0] = o0; ((float4*)op)[1] = o1;
}

// ---------------- generic split-K atomic GEMM: OUT[64t x N] += IN[64t x K] @ W[N x K]^T ----------------
// grid (N/64, K/128, L). bias (+res) folded into blockIdx.y==0 blocks. OUT must be pre-zeroed.
__global__ __launch_bounds__(256) void k_gemm64(
      const float* __restrict__ IN, const float* __restrict__ W,
      const float* __restrict__ BIAS, const float* __restrict__ RES,
      float* __restrict__ OUT, int K, int N, long wl, int bl) {
  int l = blockIdx.z;
  int n0 = blockIdx.x * 64;
  int kc0 = blockIdx.y * 128;
  const float* INl = IN + (size_t)l * 64 * K;
  const float* Wl  = W + (size_t)l * wl;
  float* OUTl = OUT + (size_t)l * 64 * N;
  __shared__ float sA[64][68], sB[64][68];
  int tid = threadIdx.x;
  int tx = tid & 15, ty = tid >> 4;
  float acc[4][4];
  if (blockIdx.y == 0) {
#pragma unroll
    for (int j = 0; j < 4; j++) {
      float bv = BIAS ? BIAS[bl * l + n0 + tx*4 + j] : 0.f;
#pragma unroll
      for (int i = 0; i < 4; i++)
        acc[i][j] = bv + (RES ? RES[((size_t)l*64 + ty*4 + i) * N + n0 + tx*4 + j] : 0.f);
    }
  } else {
#pragma unroll
    for (int i = 0; i < 4; i++)
#pragma unroll
      for (int j = 0; j < 4; j++) acc[i][j] = 0.f;
  }
  for (int kc = kc0; kc < kc0 + 128; kc += 64) {
    for (int i = tid; i < 1024; i += 256) {
      int r = i >> 4;
      int kq = i & 15;
      float4 av = *(const float4*)(INl + (size_t)r * K + kc + kq*4);
      sA[kq*4+0][r] = av.x; sA[kq*4+1][r] = av.y; sA[kq*4+2][r] = av.z; sA[kq*4+3][r] = av.w;
      float4 bv = *(const float4*)(Wl + (size_t)(n0 + r) * K + kc + kq*4);
      sB[kq*4+0][r] = bv.x; sB[kq*4+1][r] = bv.y; sB[kq*4+2][r] = bv.z; sB[kq*4+3][r] = bv.w;
    }
    __syncthreads();
#pragma unroll 8
    for (int kk = 0; kk < 64; kk++) {
      float4 a4 = *(const float4*)&sA[kk][ty*4];
      float4 b4 = *(const float4*)&sB[kk][tx*4];
      float a[4] = {a4.x,a4.y,a4.z,a4.w}, b[4] = {b4.x,b4.y,b4.z,b4.w};
#pragma unroll
      for (int i = 0; i < 4; i++)
#pragma unroll
        for (int j = 0; j < 4; j++) acc[i][j] = fmaf(a[i], b[j], acc[i][j]);
    }
    __syncthreads();
  }
#pragma unroll
  for (int i = 0; i < 4; i++)
#pragma unroll
    for (int j = 0; j < 4; j++)
      atomicAdd(&OUTl[(size_t)(ty*4+i) * N + n0 + tx*4 + j], acc[i][j]);
}

// ---------------- transposed-W variant: W stored [K][N] (for gate proj) ----------------
__global__ __launch_bounds__(256) void k_gemm64t(
      const float* __restrict__ IN, const float* __restrict__ W,
      float* __restrict__ OUT, int K, int N) {
  int l = blockIdx.z;
  int n0 = blockIdx.x * 64;
  int kc0 = blockIdx.y * 128;
  const float* INl = IN + (size_t)l * 64 * K;
  float* OUTl = OUT + (size_t)l * 64 * N;
  __shared__ float sA[64][68], sB[64][68];
  int tid = threadIdx.x;
  int tx = tid & 15, ty = tid >> 4;
  float acc[4][4] = {};
  for (int kc = kc0; kc < kc0 + 128; kc += 64) {
    for (int i = tid; i < 1024; i += 256) {
      int r = i >> 4;
      int kq = i & 15;
      float4 av = *(const float4*)(INl + (size_t)r * K + kc + kq*4);
      sA[kq*4+0][r] = av.x; sA[kq*4+1][r] = av.y; sA[kq*4+2][r] = av.z; sA[kq*4+3][r] = av.w;
      float4 bv = *(const float4*)(W + (size_t)(kc + r) * N + n0 + kq*4);
      *(float4*)&sB[r][kq*4] = bv;
    }
    __syncthreads();
#pragma unroll 8
    for (int kk = 0; kk < 64; kk++) {
      float4 a4 = *(const float4*)&sA[kk][ty*4];
      float4 b4 = *(const float4*)&sB[kk][tx*4];
      float a[4] = {a4.x,a4.y,a4.z,a4.w}, b[4] = {b4.x,b4.y,b4.z,b4.w};
#pragma unroll
      for (int i = 0; i < 4; i++)
#pragma unroll
        for (int j = 0; j < 4; j++) acc[i][j] = fmaf(a[i], b[j], acc[i][j]);
    }
    __syncthreads();
  }
#pragma unroll
  for (int i = 0; i < 4; i++)
#pragma unroll
    for (int j = 0; j < 4; j++)
      atomicAdd(&OUTl[(size_t)(ty*4+i) * N + n0 + tx*4 + j], acc[i][j]);
}

// ---------------- hd=1 attention, lanes-over-t, uniform (scalar) K/V broadcasts ----------------
__global__ __launch_bounds__(256) void k_attn(const float* __restrict__ KT, const float* __restrict__ VT,
      const float* __restrict__ Q, const float* __restrict__ kmax, const float* __restrict__ kmin,
      float* __restrict__ AO) {
  int h = blockIdx.x, l = blockIdx.y;
  int tid = threadIdx.x;
  int w = tid >> 6, t = tid & 63;
  __shared__ float pden[4][64], pnum[4][64];
  const float* kp = KT + ((size_t)(l * 512 + h)) * 4096 + w * 1024;
  const float* vp = VT + ((size_t)(l * 512 + h)) * 4096 + w * 1024;
  float q = Q[((size_t)l * TTOK + t) * 512 + h];
  float km = kmax[l * 512 + h], kn = kmin[l * 512 + h];
  float m = (q >= 0.f) ? q * km : q * kn;     // exact softmax max (hd=1)
  float d0 = 0.f, d1 = 0.f, n0 = 0.f, n1 = 0.f;
  for (int s = 0; s < 1024; s += 8) {
    float4 ka = *(const float4*)(kp + s), kb = *(const float4*)(kp + s + 4);
    float4 va = *(const float4*)(vp + s), vb = *(const float4*)(vp + s + 4);
    float e;
    e = __expf(fmaf(q, ka.x, -m)); d0 += e; n0 = fmaf(e, va.x, n0);
    e = __expf(fmaf(q, ka.y, -m)); d1 += e; n1 = fmaf(e, va.y, n1);
    e = __expf(fmaf(q, ka.z, -m)); d0 += e; n0 = fmaf(e, va.z, n0);
    e = __expf(fmaf(q, ka.w, -m)); d1 += e; n1 = fmaf(e, va.w, n1);
    e = __expf(fmaf(q, kb.x, -m)); d0 += e; n0 = fmaf(e, vb.x, n0);
    e = __expf(fmaf(q, kb.y, -m)); d1 += e; n1 = fmaf(e, vb.y, n1);
    e = __expf(fmaf(q, kb.z, -m)); d0 += e; n0 = fmaf(e, vb.z, n0);
    e = __expf(fmaf(q, kb.w, -m)); d1 += e; n1 = fmaf(e, vb.w, n1);
  }
  pden[w][t] = d0 + d1; pnum[w][t] = n0 + n1;
  __syncthreads();
  if (w == 0) {
    float d = pden[0][t] + pden[1][t] + pden[2][t] + pden[3][t];
    float n = pnum[0][t] + pnum[1][t] + pnum[2][t] + pnum[3][t];
    AO[((size_t)l * TTOK + t) * 512 + h] = n / d;
  }
}

// ---------------- gate stage 2: normalize, logits, softmax, argmax ----------------
__global__ __launch_bounds__(64) void k_gate2(const float* __restrict__ P,
      const float* __restrict__ SIM, const float* __restrict__ TEMP,
      float* __restrict__ gate, int* __restrict__ expert,
      float* __restrict__ ssum, int* __restrict__ cnt) {
  int t = blockIdx.x, l = blockIdx.y;
  int lane = threadIdx.x;
  float4 p4 = *(const float4*)(P + ((size_t)(l * 64 + t)) * 256 + lane * 4);
  float ss = p4.x*p4.x + p4.y*p4.y + p4.z*p4.z + p4.w*p4.w;
  ss = wave_sum_all(ss);
  float invp = 1.f / (sqrtf(ss) + 1e-8f);
  float le[4] = {}, ne[4] = {};
#pragma unroll
  for (int j = 0; j < 4; j++) {
    float pv = (j == 0) ? p4.x : (j == 1) ? p4.y : (j == 2) ? p4.z : p4.w;
    float4 s4 = *(const float4*)(SIM + (size_t)(lane * 4 + j) * 4);
    le[0] = fmaf(pv, s4.x, le[0]); le[1] = fmaf(pv, s4.y, le[1]);
    le[2] = fmaf(pv, s4.z, le[2]); le[3] = fmaf(pv, s4.w, le[3]);
    ne[0] = fmaf(s4.x, s4.x, ne[0]); ne[1] = fmaf(s4.y, s4.y, ne[1]);
    ne[2] = fmaf(s4.z, s4.z, ne[2]); ne[3] = fmaf(s4.w, s4.w, ne[3]);
  }
#pragma unroll
  for (int e = 0; e < 4; e++) { le[e] = wave_sum_all(le[e]); ne[e] = wave_sum_all(ne[e]); }
  if (lane == 0) {
    float scale = __expf(fminf(TEMP[0], 4.6051701859880914f));  // min(temp, log 100)
    float lg[4];
#pragma unroll
    for (int e = 0; e < 4; e++) lg[e] = le[e] * invp / (sqrtf(ne[e]) + 1e-8f) * scale;
    int best = 0; float bv = lg[0];
    if (lg[1] > bv) { best = 1; bv = lg[1]; }
    if (lg[2] > bv) { best = 2; bv = lg[2]; }
    if (lg[3] > bv) { best = 3; bv = lg[3]; }
    float mx = fmaxf(fmaxf(lg[0], lg[1]), fmaxf(lg[2], lg[3]));
    float e0 = __expf(lg[0]-mx), e1 = __expf(lg[1]-mx), e2 = __expf(lg[2]-mx), e3 = __expf(lg[3]-mx);
    float inv = 1.f / (e0 + e1 + e2 + e3);
    float s0 = e0*inv, s1 = e1*inv, s2 = e2*inv, s3 = e3*inv;
    float sb = (best == 0) ? s0 : (best == 1) ? s1 : (best == 2) ? s2 : s3;
    gate[l * TTOK + t] = sb;
    expert[l * TTOK + t] = best;
    atomicAdd(&ssum[l*4+0], s0); atomicAdd(&ssum[l*4+1], s1);
    atomicAdd(&ssum[l*4+2], s2); atomicAdd(&ssum[l*4+3], s3);
    atomicAdd(&cnt[l*4+best], 1);
  }
}

// ---------------- capacity routing ----------------
__global__ __launch_bounds__(64) void k_route(const float* __restrict__ gate, const int* __restrict__ expert,
                                              int* __restrict__ pos, int* __restrict__ keep) {
  int l = blockIdx.x;
  int t = threadIdx.x;
  __shared__ float g[64];
  __shared__ int e[64];
  g[t] = gate[l * TTOK + t]; e[t] = expert[l * TTOK + t];
  __syncthreads();
  float gt = g[t]; int et = e[t];
  int p = 0;
  for (int u = 0; u < 64; u++)
    if (e[u] == et && (g[u] > gt || (g[u] == gt && u < t))) p++;
  pos[l * TTOK + t] = p;
  keep[l * TTOK + t] = (p < CAPE) ? 1 : 0;
}

// ---------------- scatter kept tokens into expert buffers ----------------
__global__ __launch_bounds__(128) void k_scatter(const float* __restrict__ QF, const int* __restrict__ expert,
      const int* __restrict__ pos, const int* __restrict__ keep, float* __restrict__ buf) {
  int t = blockIdx.x, l = blockIdx.y;
  int idx = l * TTOK + t;
  if (!keep[idx]) return;
  int e = expert[idx], p = pos[idx];
  const float4* src = (const float4*)(QF + ((size_t)l * TTOK + t) * 512);
  float4* dst = (float4*)(buf + (((size_t)(l * 4 + e)) * CAPE + p) * 512);
  dst[threadIdx.x] = src[threadIdx.x];
}

// ---------------- expert up-proj + exact gelu (acts via uniform s_loads) ----------------
__global__ __launch_bounds__(256) void k_moe_h(const float* __restrict__ buf, const float* __restrict__ W1,
      const float* __restrict__ B1, float* __restrict__ H) {
  int le = blockIdx.y;             // l*4 + e
  int e = le & 3;
  int col = blockIdx.x * 256 + threadIdx.x;
  const float* act = buf + (size_t)le * 16 * 512;          // wave-uniform
  const float* wp = W1 + (size_t)e * 512 * HIDE + col;
  float acc[16];
#pragma unroll
  for (int c = 0; c < 16; c++) acc[c] = 0.f;
  for (int k0 = 0; k0 < 512; k0 += 4) {
    float4 a[16];
#pragma unroll
    for (int c = 0; c < 16; c++) a[c] = *(const float4*)(act + c * 512 + k0);
#pragma unroll
    for (int j = 0; j < 4; j++) {
      float wv = wp[(size_t)(k0 + j) * HIDE];
#pragma unroll
      for (int c = 0; c < 16; c++) acc[c] = fmaf(((const float*)&a[c])[j], wv, acc[c]);
    }
  }
  float bias = B1[e * HIDE + col];
  float* outp = H + (size_t)le * 16 * HIDE + col;
#pragma unroll
  for (int c = 0; c < 16; c++) {
    float v = acc[c] + bias;
    outp[(size_t)c * HIDE] = 0.5f * v * (1.f + erff(v * 0.70710678118654752f));
  }
}

// ---------------- expert down-proj (k split across 4 waves, LDS reduce) ----------------
__global__ __launch_bounds__(256) void k_moe_y(const float* __restrict__ H, const float* __restrict__ W2,
      const float* __restrict__ B2, float* __restrict__ Y) {
  int le = blockIdx.y;
  int e = le & 3;
  int cl = threadIdx.x & 63, kq = threadIdx.x >> 6;
  int col = blockIdx.x * 64 + cl;
  const float* act = H + (size_t)le * 16 * HIDE + kq * 512;   // wave-uniform
  const float* wp = W2 + (size_t)e * HIDE * 512 + (size_t)(kq * 512) * 512 + col;
  float acc[16];
#pragma unroll
  for (int c = 0; c < 16; c++) acc[c] = 0.f;
  for (int k0 = 0; k0 < 512; k0 += 4) {
    float4 a[16];
#pragma unroll
    for (int c = 0; c < 16; c++) a[c] = *(const float4*)(act + c * HIDE + k0);
#pragma unroll
    for (int j = 0; j < 4; j++) {
      float wv = wp[(size_t)(k0 + j) * 512];
#pragma unroll
      for (int c = 0; c < 16; c++) acc[c] = fmaf(((const float*)&a[c])[j], wv, acc[c]);
    }
  }
  __shared__ float sacc[4][16][64];
#pragma unroll
  for (int c = 0; c < 16; c++) sacc[kq][c][cl] = acc[c];
  __syncthreads();
  if (kq == 0) {
    float bias = B2[e * 512 + col];
#pragma unroll
    for (int c = 0; c < 16; c++) {
      float tot = sacc[0][c][cl] + sacc[1][c][cl] + sacc[2][c][cl] + sacc[3][c][cl] + bias;
      Y[(size_t)le * 16 * 512 + (size_t)c * 512 + col] = tot;
    }
  }
}

// ---------------- gather expert outputs, prefix over layers ----------------
__global__ __launch_bounds__(512) void k_combine(const float* __restrict__ Y, const int* __restrict__ expert,
      const int* __restrict__ pos, const int* __restrict__ keep, const float* __restrict__ gate,
      float* __restrict__ f1, float* __restrict__ f2, float* __restrict__ cur) {
  int t = blockIdx.x;
  int d = threadIdx.x;
  float acc = 0.f;
#pragma unroll
  for (int l = 0; l < LNUM; l++) {
    int idx = l * TTOK + t;
    float v = 0.f;
    if (keep[idx]) {
      int e = expert[idx], p = pos[idx];
      v = Y[(((size_t)(l * 4 + e)) * CAPE + p) * 512 + d] * gate[idx];
    }
    acc += v;
    f1[((size_t)l * TTOK + t) * 512 + d] = acc;
    f2[((size_t)l * TTOK + t) * 512 + d] = 0.f;
  }
  cur[(size_t)t * 512 + d] = acc * 0.25f;
}

// ---------------- GSA attention (8 heads, hd=64), reads fused QKV3 [64][1536] ----------------
__global__ __launch_bounds__(256) void k_gsa_attn(const float* __restrict__ QKV3, float* __restrict__ AO2) {
  int h = blockIdx.x;
  __shared__ float qh[64][65], kh[64][65], vh[64][65];
  __shared__ float ps[4][64];
  for (int i = threadIdx.x; i < 4096; i += 256) {
    int t = i >> 6, d = i & 63;
    qh[t][d] = QKV3[(size_t)t * 1536 + h * 64 + d];
    kh[t][d] = QKV3[(size_t)t * 1536 + 512 + h * 64 + d];
    vh[t][d] = QKV3[(size_t)t * 1536 + 1024 + h * 64 + d];
  }
  __syncthreads();
  int w = threadIdx.x >> 6, lane = threadIdx.x & 63;
  for (int tt = 0; tt < 16; tt++) {
    int t = w * 16 + tt;
    float acc = 0.f;
#pragma unroll 8
    for (int d = 0; d < 64; d++) acc = fmaf(qh[t][d], kh[lane][d], acc);
    acc *= 0.125f;
    float m = acc;
#pragma unroll
    for (int o = 32; o > 0; o >>= 1) m = fmaxf(m, __shfl_xor(m, o, 64));
    float e = __expf(acc - m);
    float den = e;
#pragma unroll
    for (int o = 32; o > 0; o >>= 1) den += __shfl_xor(den, o, 64);
    ps[w][lane] = e / den;
    __syncthreads();
    float o2 = 0.f;
#pragma unroll 8
    for (int s = 0; s < 64; s++) o2 = fmaf(ps[w][s], vh[s][lane], o2);
    AO2[(size_t)t * 512 + h * 64 + lane] = o2;
    __syncthreads();
  }
}

// ---------------- swish in-place ----------------
__global__ __launch_bounds__(256) void k_swish(float* __restrict__ H) {
  int i = blockIdx.x * 256 + threadIdx.x;
  float x = H[i];
  H[i] = x / (1.f + __expf(-1.702f * x));
}

// ---------------- classifier head + hazards + Y_hat + aux + feature2_pre ----------------
__global__ __launch_bounds__(256) void k_final(const float* __restrict__ HB,
      const float* __restrict__ CW, const float* __restrict__ CB,
      const float* __restrict__ ssum, const int* __restrict__ cnt,
      float* __restrict__ out) {
  int tid = threadIdx.x;
  float p0 = 0.f, p1 = 0.f;
  for (int i = tid; i < 16384; i += 256) {
    float h = HB[i];
    p0 = fmaf(h, CW[i], p0);
    p1 = fmaf(h, CW[16384 + i], p1);
  }
  p0 = block_sum256(p0);
  p1 = block_sum256(p1);
  if (tid == 0) {
    float l0 = p0 + CB[0], l1 = p1 + CB[1];
    out[0] = l0; out[1] = l1;
    out[2] = 1.f / (1.f + __expf(-l0));
    out[3] = 1.f / (1.f + __expf(-l1));
    out[4] = (l1 > l0) ? 1.f : 0.f;
    float aux = 0.f;
    for (int i = 0; i < 16; i++) aux += (ssum[i] * (1.f / 64.f)) * ((float)cnt[i] * (1.f / 64.f));
    out[5] = aux * 4.f * 0.01f;
  }
  if (tid < 8) out[O_F2P + tid] = 0.f;
}

extern "C" void kernel_launch(void* const* d_in, const int* in_sizes, int n_in,
                              void* d_out, int out_size, void* d_ws, size_t ws_size,
                              hipStream_t stream) {
  const float* SF    = (const float*)d_in[0];
  const float* TOK   = (const float*)d_in[1];
  const float* LN1G  = (const float*)d_in[2];
  const float* LN1B  = (const float*)d_in[3];
  const float* LN2G  = (const float*)d_in[4];
  const float* LN2B  = (const float*)d_in[5];
  const float* QKVW  = (const float*)d_in[6];
  const float* QKVB  = (const float*)d_in[7];
  const float* OUTW  = (const float*)d_in[8];
  const float* OUTB  = (const float*)d_in[9];
  const float* MLPW  = (const float*)d_in[10];
  const float* MLPB  = (const float*)d_in[11];
  const float* GPW   = (const float*)d_in[12];
  const float* GSIM  = (const float*)d_in[13];
  const float* GTMP  = (const float*)d_in[14];
  const float* EW1   = (const float*)d_in[15];
  const float* EB1   = (const float*)d_in[16];
  const float* EW2   = (const float*)d_in[17];
  const float* EB2   = (const float*)d_in[18];
  const float* GL1G  = (const float*)d_in[19];
  const float* GL1B  = (const float*)d_in[20];
  const float* GQKVW = (const float*)d_in[21];
  const float* GQKVB = (const float*)d_in[22];
  const float* GOUTW = (const float*)d_in[23];
  const float* GOUTB = (const float*)d_in[24];
  const float* GL2G  = (const float*)d_in[25];
  const float* GL2B  = (const float*)d_in[26];
  const float* GFCW  = (const float*)d_in[27];
  const float* GFCB  = (const float*)d_in[28];
  const float* GPJW  = (const float*)d_in[29];
  const float* GPJB  = (const float*)d_in[30];
  const float* BTW   = (const float*)d_in[31];
  const float* BTB   = (const float*)d_in[32];
  const float* CLW   = (const float*)d_in[33];
  const float* CLB   = (const float*)d_in[34];

  float* ws  = (float*)d_ws;
  float* out = (float*)d_out;

  float* BUF  = ws + OFF_BUF;
  float* SSUM = ws + OFF_SSUM;
  int*   CNT  = (int*)(ws + OFF_CNT);
  float* Q    = ws + OFF_Q;
  float* AP   = ws + OFF_AP;
  float* QF   = ws + OFF_QF;
  float* P    = ws + OFF_P;
  float* QKV3 = ws + OFF_QKV3;
  float* XB   = ws + OFF_XB;
  float* HROW = ws + OFF_HROW;
  float* GTD  = ws + OFF_GTD;
  float* HBB  = ws + OFF_HB;
  float* KT   = ws + OFF_KT;
  float* VT   = ws + OFF_VT;
  float* KMAX = ws + OFF_KMAX;
  float* KMIN = ws + OFF_KMIN;
  float* AOSH = ws + OFF_AO;      // shared TN / AO / XN2 / XN3 (sequential lifetimes)
  float* GATE = ws + OFF_GATE;
  int*   EXPI = (int*)(ws + OFF_EXP);
  int*   POSI = (int*)(ws + OFF_POS);
  int*   KEEPI= (int*)(ws + OFF_KEEP);
  float* HEXP = ws + OFF_HEXP;
  float* CUR  = ws + OFF_CUR;
  float* AO2  = ws + OFF_AO2;
  bf16*  AH   = (bf16*)(ws + OFF_AH);
  bf16*  AL   = (bf16*)(ws + OFF_AL);
  bf16*  WH   = (bf16*)(ws + OFF_WH);
  bf16*  WL   = (bf16*)(ws + OFF_WL);
  float* YEXP = ws + OFF_YEXP;    // aliases AH (dead after k_mfma_kv)

  // zero all atomic-GEMM outputs + MoE scratch
  k_zero<<<(ZERO_N + 255) / 256, 256, 0, stream>>>(ws, ZERO_N);
  // K/V projection via split-bf16 MFMA
  k_cvt_a<<<LNUM * NSEQ, 64, 0, stream>>>(SF, LN1G, LN1B, AH, AL);
  k_cvt_w<<<LNUM * 1024, 64, 0, stream>>>(QKVW, WH, WL);
  k_mfma_kv<<<dim3(8, 32, LNUM), 256, 0, stream>>>(AH, AL, WH, WL, QKVB, KT, VT);
  k_minmax<<<LNUM * 512, 256, 0, stream>>>(KT, KMAX, KMIN);
  // Q projection: LN(tok) -> TN(=AOSH), then GEMM
  k_ln<<<dim3(TTOK, LNUM), 64, 0, stream>>>(TOK, LN2G, LN2B, AOSH, 512);
  k_gemm64<<<dim3(8, 4, LNUM), 256, 0, stream>>>(AOSH, QKVW, QKVB, nullptr, Q, 512, 512, 1536L*512, 1536);
  // hd=1 attention (overwrites AOSH with AO)
  k_attn<<<dim3(512, LNUM), 256, 0, stream>>>(KT, VT, Q, KMAX, KMIN, AOSH);
  // out-proj and mlp
  k_gemm64<<<dim3(8, 4, LNUM), 256, 0, stream>>>(AOSH, OUTW, OUTB, nullptr, AP, 512, 512, 512L*512, 512);
  k_gemm64<<<dim3(8, 4, LNUM), 256, 0, stream>>>(AP, MLPW, MLPB, nullptr, QF, 512, 512, 512L*512, 512);
  // MoE gating + routing
  k_gemm64t<<<dim3(4, 4, LNUM), 256, 0, stream>>>(QF, GPW, P, 512, 256);
  k_gate2<<<dim3(TTOK, LNUM), 64, 0, stream>>>(P, GSIM, GTMP, GATE, EXPI, SSUM, CNT);
  k_route<<<LNUM, 64, 0, stream>>>(GATE, EXPI, POSI, KEEPI);
  k_scatter<<<dim3(TTOK, LNUM), 128, 0, stream>>>(QF, EXPI, POSI, KEEPI, BUF);
  k_moe_h<<<dim3(8, 16), 256, 0, stream>>>(BUF, EW1, EB1, HEXP);
  k_moe_y<<<dim3(8, 16), 256, 0, stream>>>(HEXP, EW2, EB2, YEXP);
  k_combine<<<TTOK, 512, 0, stream>>>(YEXP, EXPI, POSI, KEEPI, GATE, out + O_F1, out + O_F2, CUR);
  // GSA block
  k_ln<<<dim3(TTOK, 1), 64, 0, stream>>>(CUR, GL1G, GL1B, AOSH, 0);             // XN2 in AOSH
  k_gemm64<<<dim3(24, 4, 1), 256, 0, stream>>>(AOSH, GQKVW, GQKVB, nullptr, QKV3, 512, 1536, 0, 0);
  k_gsa_attn<<<8, 256, 0, stream>>>(QKV3, AO2);
  k_gemm64<<<dim3(8, 4, 1), 256, 0, stream>>>(AO2, GOUTW, GOUTB, CUR, XB, 512, 512, 0, 0);
  k_ln<<<dim3(TTOK, 1), 64, 0, stream>>>(XB, GL2G, GL2B, AOSH, 0);              // XN3 in AOSH
  k_gemm64<<<dim3(32, 4, 1), 256, 0, stream>>>(AOSH, GFCW, GFCB, nullptr, HROW, 512, 2048, 0, 0);
  k_swish<<<(TTOK * HIDE) / 256, 256, 0, stream>>>(HROW);
  k_gemm64<<<dim3(8, 16, 1), 256, 0, stream>>>(HROW, GPJW, GPJB, XB, GTD, 2048, 512, 0, 0);
  k_gemm64<<<dim3(4, 4, 1), 256, 0, stream>>>(GTD, BTW, BTB, nullptr, HBB, 512, 256, 0, 0);
  k_final<<<1, 256, 0, stream>>>(HBB, CLW, CLB, SSUM, CNT, out);
}